// Round 8
// baseline (241.789 us; speedup 1.0000x reference)
//
#include <hip/hip_runtime.h>
#include <hip/hip_bf16.h>

typedef __hip_bfloat16 bf16;
typedef __attribute__((ext_vector_type(8))) short short8;
typedef __attribute__((ext_vector_type(4))) float floatx4;

#define NB 16

// drug conv chain:  L 64 ->61(K4,C40) ->56(K6,C80) ->49(K8,C160)
// prot conv chain:  L 1200 ->1197(K4,C40) ->1190(K8,C80) ->1179(K12,C160)

__device__ __forceinline__ float b2f(bf16 x) { return __bfloat162float(x); }
__device__ __forceinline__ float u16bf(unsigned short u) {
    return __uint_as_float(((unsigned)u) << 16);
}
__device__ __forceinline__ unsigned short f2bu(float v) {
    union { bf16 h; unsigned short u; } cv;
    cv.h = __float2bfloat16(v);
    return cv.u;
}

// ---------------- dtype sniffer (R4-proven) ----------------
__global__ void sniff_kernel(const unsigned short* __restrict__ w, int* __restrict__ flag) {
    __shared__ int cnt;
    if (threadIdx.x == 0) cnt = 0;
    __syncthreads();
    int hits = 0;
    for (int s = 0; s < 4; s++) {
        unsigned short u = w[(threadIdx.x * 4 + s) * 2];
        float v = fabsf(u16bf(u));
        if (v > 1e-6f && v < 2.0f) hits++;
    }
    atomicAdd(&cnt, hits);
    __syncthreads();
    if (threadIdx.x == 0) *flag = (cnt > 512) ? 1 : 0;
}

// ---------------- unified prep: bias cvt (f32) + bf16 packs in ONE dispatch ----------------
#define NSEG 14
struct CvtJob {
    const void* src[NSEG];
    float* dst[NSEG];
    int n[NSEG];
};
#define NPK 11
struct PackJob {
    const void* src[NPK];
    bf16* dst[NPK];
    short Cout[NPK], CIN[NPK], K[NPK], coP[NPK], CIP[NPK];
};

__global__ void prep(CvtJob cj, PackJob pj, const int* __restrict__ flagp) {
    int y = blockIdx.y;
    int i = blockIdx.x * 256 + threadIdx.x;
    if (y < NSEG) {
        if (i >= cj.n[y]) return;
        const void* s = cj.src[y];
        if (s == nullptr) { cj.dst[y][i] = 0.f; return; }
        cj.dst[y][i] = (*flagp) ? b2f(((const bf16*)s)[i]) : ((const float*)s)[i];
    } else {
        int p = y - NSEG;
        int Cout = pj.Cout[p], CIN = pj.CIN[p], K = pj.K[p];
        int coP = pj.coP[p], CIP = pj.CIP[p];
        int total = K * coP * CIP;
        if (i >= total) return;
        int ci = i % CIP;
        int t = i / CIP;
        int co = t % coP;
        int k = t / coP;
        float v = 0.f;
        if (co < Cout && ci < CIN) {
            int s = (co * CIN + ci) * K + k;
            v = (*flagp) ? b2f(((const bf16*)pj.src[p])[s]) : ((const float*)pj.src[p])[s];
        }
        pj.dst[p][i] = __float2bfloat16(v);
    }
}

// ---------------- conv via MFMA implicit GEMM: shared body (v10-proven) ----------------
template <int K, int CIN, int CHUNKS, int NW>
__device__ __forceinline__ void conv_body(unsigned short* xT,
                                          const unsigned short* xb,
                                          const unsigned short* wbase,
                                          const float* __restrict__ bias,
                                          bf16* __restrict__ y,
                                          int b, int Lin, int Lout,
                                          int Cout, int coP, int l0) {
    const int CIP = CHUNKS * 32;
    const int PCI = CIP + 8;
    const int TLX = 64 + K - 1;
    for (int i = threadIdx.x; i < TLX * CIP; i += NW * 64) {
        int ci = i / TLX, l = i - ci * TLX;
        unsigned short v = 0;
        int gl = l0 + l;
        if (ci < CIN && gl < Lin) v = xb[ci * Lin + gl];
        xT[l * PCI + ci] = v;
    }
    __syncthreads();
    int lane = threadIdx.x & 63;
    int ct = threadIdx.x >> 6;       // wave id == ct tile
    int n = lane & 15, quad = lane >> 4;
    floatx4 acc[4];
#pragma unroll
    for (int i = 0; i < 4; i++) acc[i] = (floatx4){0.f, 0.f, 0.f, 0.f};
#pragma unroll
    for (int k = 0; k < K; k++) {
#pragma unroll
        for (int ch = 0; ch < CHUNKS; ch++) {
            short8 a = *(const short8*)(wbase +
                        ((size_t)(k * coP + ct * 16 + n)) * CIP + ch * 32 + quad * 8);
#pragma unroll
            for (int nt = 0; nt < 4; nt++) {
                short8 bb = *(const short8*)(xT + (nt * 16 + n + k) * PCI + ch * 32 + quad * 8);
                acc[nt] = __builtin_amdgcn_mfma_f32_16x16x32_bf16(a, bb, acc[nt], 0, 0, 0);
            }
        }
    }
    int m0 = quad * 4;
#pragma unroll
    for (int nt = 0; nt < 4; nt++) {
        int l = l0 + nt * 16 + n;
        if (l >= Lout) continue;
#pragma unroll
        for (int r = 0; r < 4; r++) {
            int co = ct * 16 + m0 + r;
            if (co < Cout)
                y[((size_t)b * Cout + co) * Lout + l] =
                    __float2bfloat16(fmaxf(acc[nt][r] + bias[co], 0.f));
        }
    }
}

// merged drug+prot conv (layer 2), NW waves = NW ct-tiles (v10-proven)
template <int KD, int KP, int CIN, int CHUNKS, int NW>
__global__ __launch_bounds__(NW * 64) void conv_dual(const bf16* __restrict__ xd,
                                                 const bf16* __restrict__ Wpd,
                                                 const float* __restrict__ bd,
                                                 bf16* __restrict__ yd, int LinD, int LoutD,
                                                 const bf16* __restrict__ xp,
                                                 const bf16* __restrict__ Wpp,
                                                 const float* __restrict__ bp,
                                                 bf16* __restrict__ yp, int LinP, int LoutP,
                                                 int Cout, int coP) {
    const int CIP = CHUNKS * 32;
    const int PCI = CIP + 8;
    const int TLXMAX = 64 + KP - 1;   // KP >= KD
    __shared__ __align__(16) unsigned short xT[TLXMAX * PCI];
    if (blockIdx.x < 16) {
        int b = blockIdx.x;
        conv_body<KD, CIN, CHUNKS, NW>(xT, (const unsigned short*)xd + (size_t)b * CIN * LinD,
                                   (const unsigned short*)Wpd, bd, yd, b, LinD, LoutD,
                                   Cout, coP, 0);
    } else {
        int bx = blockIdx.x - 16;
        int b = bx / 19, l0 = (bx % 19) << 6;
        conv_body<KP, CIN, CHUNKS, NW>(xT, (const unsigned short*)xp + (size_t)b * CIN * LinP,
                                   (const unsigned short*)Wpp, bp, yp, b, LinP, LoutP,
                                   Cout, coP, l0);
    }
}

// ---------------- conv3 + att_proj FUSED ----------------
// Tile identity: conv3 block (b,l0) produces exactly the 160x64 tile att_proj
// block (b,l0) consumed. v11: conv epilogue writes relu'd tile (zero-padded past
// Lout) into LDS xP, barrier, then the projection MFMA runs in the same block,
// writing datt/pattB directly. Removes one dispatch + one global staging pass.
// NW*16 == Cout (=160) so no co guard.
template <int K, int CIN, int CHUNKS, int NW>
__device__ __forceinline__ void conv_proj_phase(unsigned short* xT, unsigned short* xP,
                                                const unsigned short* xb,
                                                const unsigned short* wbase,
                                                const float* __restrict__ bias,
                                                unsigned short* __restrict__ y,
                                                int b, int Lin, int Lout,
                                                int Cout, int coP, int l0) {
    const int CIP = CHUNKS * 32;
    const int PCI = CIP + 8;
    const int TLX = 64 + K - 1;
    for (int i = threadIdx.x; i < TLX * CIP; i += NW * 64) {
        int ci = i / TLX, l = i - ci * TLX;
        unsigned short v = 0;
        int gl = l0 + l;
        if (ci < CIN && gl < Lin) v = xb[ci * Lin + gl];
        xT[l * PCI + ci] = v;
    }
    __syncthreads();
    int lane = threadIdx.x & 63;
    int ct = threadIdx.x >> 6;
    int n = lane & 15, quad = lane >> 4;
    floatx4 acc[4];
#pragma unroll
    for (int i = 0; i < 4; i++) acc[i] = (floatx4){0.f, 0.f, 0.f, 0.f};
#pragma unroll
    for (int k = 0; k < K; k++) {
#pragma unroll
        for (int ch = 0; ch < CHUNKS; ch++) {
            short8 a = *(const short8*)(wbase +
                        ((size_t)(k * coP + ct * 16 + n)) * CIP + ch * 32 + quad * 8);
#pragma unroll
            for (int nt = 0; nt < 4; nt++) {
                short8 bb = *(const short8*)(xT + (nt * 16 + n + k) * PCI + ch * 32 + quad * 8);
                acc[nt] = __builtin_amdgcn_mfma_f32_16x16x32_bf16(a, bb, acc[nt], 0, 0, 0);
            }
        }
    }
    int m0 = quad * 4;
#pragma unroll
    for (int nt = 0; nt < 4; nt++) {
        int ll = nt * 16 + n;
        int l = l0 + ll;
#pragma unroll
        for (int r = 0; r < 4; r++) {
            int co = ct * 16 + m0 + r;
            float val = (l < Lout) ? fmaxf(acc[nt][r] + bias[co], 0.f) : 0.f;
            unsigned short u = f2bu(val);
            xP[ll * 168 + co] = u;                          // proj input tile
            if (l < Lout) y[((size_t)b * Cout + co) * Lout + l] = u;  // for att_sig
        }
    }
}

template <int KD, int KP, int CIN, int CHUNKS, int NW>
__global__ __launch_bounds__(NW * 64) void conv3_proj(
        const bf16* __restrict__ xd, const bf16* __restrict__ Wpd,
        const float* __restrict__ bd, bf16* __restrict__ yd, int LinD, int LoutD,
        const bf16* __restrict__ xp, const bf16* __restrict__ Wpp,
        const float* __restrict__ bp, bf16* __restrict__ yp, int LinP, int LoutP,
        int Cout, int coP,
        const bf16* __restrict__ dWB, const bf16* __restrict__ pWB,
        const float* __restrict__ dbF, const float* __restrict__ pbF,
        float* __restrict__ datt, bf16* __restrict__ pattB) {
    const int CIP = CHUNKS * 32;
    const int PCI = CIP + 8;
    const int TLXMAX = 64 + KP - 1;
    __shared__ __align__(16) unsigned short xT[TLXMAX * PCI];
    __shared__ __align__(16) unsigned short xP[64 * 168];
    bool isD = blockIdx.x < 16;
    int b, l0, L;
    if (isD) {
        b = blockIdx.x; l0 = 0; L = LoutD;
        conv_proj_phase<KD, CIN, CHUNKS, NW>(xT, xP,
            (const unsigned short*)xd + (size_t)b * CIN * LinD,
            (const unsigned short*)Wpd, bd, (unsigned short*)yd, b, LinD, LoutD, Cout, coP, 0);
    } else {
        int bx = blockIdx.x - 16;
        b = bx / 19; l0 = (bx % 19) << 6; L = LoutP;
        conv_proj_phase<KP, CIN, CHUNKS, NW>(xT, xP,
            (const unsigned short*)xp + (size_t)b * CIN * LinP,
            (const unsigned short*)Wpp, bp, (unsigned short*)yp, b, LinP, LoutP, Cout, coP, l0);
    }
    __syncthreads();
    // projection phase: wave t owns output tile t (0..NW-1), reads xP
    int lane = threadIdx.x & 63;
    int t = threadIdx.x >> 6;
    int n = lane & 15, quad = lane >> 4;
    const unsigned short* W = (const unsigned short*)(isD ? dWB : pWB);
    const float* pbias = isD ? dbF : pbF;
    floatx4 acc[4];
#pragma unroll
    for (int i = 0; i < 4; i++) acc[i] = (floatx4){0.f, 0.f, 0.f, 0.f};
#pragma unroll
    for (int ch = 0; ch < 5; ch++) {
        short8 a = *(const short8*)(W + ((size_t)(t * 16 + n)) * 160 + ch * 32 + quad * 8);
#pragma unroll
        for (int nt = 0; nt < 4; nt++) {
            short8 bb = *(const short8*)(xP + (nt * 16 + n) * 168 + ch * 32 + quad * 8);
            acc[nt] = __builtin_amdgcn_mfma_f32_16x16x32_bf16(a, bb, acc[nt], 0, 0, 0);
        }
    }
    int m0 = quad * 4;
    int o0 = t * 16 + m0;
#pragma unroll
    for (int nt = 0; nt < 4; nt++) {
        int l = l0 + nt * 16 + n;
        if (l >= L) continue;
        if (isD) {
            float4 v;
            v.x = acc[nt][0] + pbias[o0 + 0];
            v.y = acc[nt][1] + pbias[o0 + 1];
            v.z = acc[nt][2] + pbias[o0 + 2];
            v.w = acc[nt][3] + pbias[o0 + 3];
            *(float4*)(datt + ((size_t)b * 49 + l) * 160 + o0) = v;
        } else {
            ushort4 u;
            u.x = f2bu(acc[nt][0] + pbias[o0 + 0]);
            u.y = f2bu(acc[nt][1] + pbias[o0 + 1]);
            u.z = f2bu(acc[nt][2] + pbias[o0 + 2]);
            u.w = f2bu(acc[nt][3] + pbias[o0 + 3]);
            *(ushort4*)((unsigned short*)pattB + ((size_t)b * 1179 + l) * 160 + o0) = u;
        }
    }
}

// ---------------- conv1 via MFMA with embedding-gather staging (R10-proven) ----------------
__global__ __launch_bounds__(256) void conv1_mfma(const int* __restrict__ dtok,
                                                  const int* __restrict__ ptok,
                                                  const bf16* __restrict__ embDB,
                                                  const bf16* __restrict__ embPB,
                                                  const bf16* __restrict__ dW1p,
                                                  const bf16* __restrict__ pW1p,
                                                  const float* __restrict__ db1f,
                                                  const float* __restrict__ pb1f,
                                                  bf16* __restrict__ d1,
                                                  bf16* __restrict__ p1) {
    const int K = 4, CIP = 64, PCI = 72, TLX = 67, coP = 48, Cout = 40;
    __shared__ __align__(16) unsigned short xT[TLX * PCI];
    __shared__ int stok[TLX];
    bool isD = blockIdx.x < 16;
    int b, l0, Lin, Lout;
    const int* tok; const unsigned short* embB; const unsigned short* Wp;
    const float* bias; bf16* y;
    if (isD) {
        b = blockIdx.x; l0 = 0; Lin = 64; Lout = 61;
        tok = dtok; embB = (const unsigned short*)embDB;
        Wp = (const unsigned short*)dW1p; bias = db1f; y = d1;
    } else {
        int bx = blockIdx.x - 16;
        b = bx / 19; l0 = (bx % 19) << 6; Lin = 1200; Lout = 1197;
        tok = ptok; embB = (const unsigned short*)embPB;
        Wp = (const unsigned short*)pW1p; bias = pb1f; y = p1;
    }
    if (threadIdx.x < TLX) {
        int l = l0 + threadIdx.x;
        stok[threadIdx.x] = (l < Lin) ? tok[b * Lin + l] : -1;
    }
    __syncthreads();
    for (int i = threadIdx.x; i < TLX * CIP; i += 256) {
        int ci = i / TLX, l = i - ci * TLX;
        int t = stok[l];
        xT[l * PCI + ci] = (t >= 0) ? embB[t * 64 + ci] : (unsigned short)0;
    }
    __syncthreads();
    int lane = threadIdx.x & 63;
    int w = threadIdx.x >> 6;
    int n = lane & 15, quad = lane >> 4;
    if (w >= 3) return;
    floatx4 acc[4];
#pragma unroll
    for (int i = 0; i < 4; i++) acc[i] = (floatx4){0.f, 0.f, 0.f, 0.f};
#pragma unroll
    for (int k = 0; k < K; k++) {
#pragma unroll
        for (int ch = 0; ch < 2; ch++) {
            short8 a = *(const short8*)(Wp +
                        ((size_t)(k * coP + w * 16 + n)) * CIP + ch * 32 + quad * 8);
#pragma unroll
            for (int nt = 0; nt < 4; nt++) {
                short8 bb = *(const short8*)(xT + (nt * 16 + n + k) * PCI + ch * 32 + quad * 8);
                acc[nt] = __builtin_amdgcn_mfma_f32_16x16x32_bf16(a, bb, acc[nt], 0, 0, 0);
            }
        }
    }
    int m0 = quad * 4;
#pragma unroll
    for (int nt = 0; nt < 4; nt++) {
        int l = l0 + nt * 16 + n;
        if (l >= Lout) continue;
#pragma unroll
        for (int r = 0; r < 4; r++) {
            int co = w * 16 + m0 + r;
            if (co < Cout)
                y[((size_t)b * Cout + co) * Lout + l] =
                    __float2bfloat16(fmaxf(acc[nt][r] + bias[co], 0.f));
        }
    }
}

// ---------------- fused means v9: 4-way d-split for 2x TLP (proven) ----------------
__global__ __launch_bounds__(640) void mean_fused(const float* __restrict__ datt,
                                                  const bf16* __restrict__ patt,
                                                  bf16* __restrict__ MpW,
                                                  float* __restrict__ Mdpart) {
    __shared__ __align__(16) unsigned short sp[37 * 160];
    int tid = threadIdx.x;
    int b = blockIdx.x >> 5;          // / 32
    int pc = blockIdx.x & 31;
    int p0 = pc * 37;                 // 32 chunks of 37 cover 1179 (last: 32 valid)
    int pmax = 1179 - p0;
    if (pmax > 37) pmax = 37;
    // stage p-tile (coalesced short8): sp[pi][k] = patt[b][p0+pi][k]
    {
        const short8* src = (const short8*)((const unsigned short*)patt +
                                            ((size_t)b * 1179 + p0) * 160);
        short8* dst = (short8*)sp;
        int n8 = (pmax * 160) >> 3;   // multiple of 20, exact
        for (int v = tid; v < n8; v += 640) dst[v] = src[v];
    }
    int h = tid & 3;
    int k = tid >> 2;                 // 0..159
    int d0 = h * 13;                  // 0,13,26,39
    int nd = (h == 3) ? 10 : 13;      // 13+13+13+10 = 49
    const float* drow = datt + (size_t)b * 49 * 160 + k;
    float dv[13], md[13];
#pragma unroll
    for (int i = 0; i < 13; i++) {
        // pad slots: dv=-1e30 -> relu(dv+pv)==0, contributes nothing
        dv[i] = (i < nd) ? drow[(d0 + i) * 160] : -1e30f;
        md[i] = 0.f;
    }
    __syncthreads();
    unsigned short* mp = (unsigned short*)MpW + ((size_t)b * 1184 + p0) * 160 + k;
#pragma unroll 2
    for (int pi = 0; pi < pmax; pi++) {
        float pv = u16bf(sp[pi * 160 + k]);
        float s0 = 0.f, s1 = 0.f, s2 = 0.f, s3 = 0.f;
#pragma unroll
        for (int g = 0; g < 3; g++) {
            float r0 = fmaxf(dv[g * 4 + 0] + pv, 0.f);
            float r1 = fmaxf(dv[g * 4 + 1] + pv, 0.f);
            float r2 = fmaxf(dv[g * 4 + 2] + pv, 0.f);
            float r3 = fmaxf(dv[g * 4 + 3] + pv, 0.f);
            md[g * 4 + 0] += r0; s0 += r0;
            md[g * 4 + 1] += r1; s1 += r1;
            md[g * 4 + 2] += r2; s2 += r2;
            md[g * 4 + 3] += r3; s3 += r3;
        }
        {
            float r = fmaxf(dv[12] + pv, 0.f);
            md[12] += r; s0 += r;
        }
        float s = (s0 + s1) + (s2 + s3);
        s += __shfl_xor(s, 1, 64);    // combine 4 d-quarters (lanes 4k..4k+3)
        s += __shfl_xor(s, 2, 64);
        if (h == 0) mp[(size_t)pi * 160] = f2bu(s * (1.f / 49.f));
    }
    // streaming partial store: [b][pc][d][k], wave-coalesced runs, no RMW
    float* op = Mdpart + (((size_t)b * 32 + pc) * 49) * 160 + k;
#pragma unroll
    for (int i = 0; i < 13; i++)
        if (i < nd) op[(d0 + i) * 160] = md[i];
}

// ---------------- att_sig via MFMA + fused sigmoid/scale/maxpool ----------------
// v11: md_reduce folded into the d-path staging (sums 32 Mdpart partials inline;
// hidden under the 304 p-blocks). Md buffer eliminated.
__global__ __launch_bounds__(640) void att_sig_mfma(const float* __restrict__ Mdpart,
                                                    const bf16* __restrict__ MpW,
                                                    const bf16* __restrict__ wattB,
                                                    const float* __restrict__ attbF,
                                                    const bf16* __restrict__ dcB,
                                                    const bf16* __restrict__ pcB,
                                                    float* __restrict__ pair) {
    const int PCI = 168;
    __shared__ __align__(16) unsigned short sM[64 * PCI];
    bool isD = blockIdx.x < 16;
    int b, p0, L, off;
    const unsigned short* conv;
    if (isD) {
        b = blockIdx.x; p0 = 0; L = 49; off = 0; conv = (const unsigned short*)dcB;
        const float* mdp = Mdpart + (size_t)b * 32 * 49 * 160;
        for (int i = threadIdx.x; i < 160 * 64; i += 640) {
            int r = i / 160, k = i - r * 160;
            float v = 0.f;
            if (r < 49) {
                const float* src = mdp + r * 160 + k;
                float s0 = 0.f, s1 = 0.f, s2 = 0.f, s3 = 0.f;
#pragma unroll
                for (int pc = 0; pc < 32; pc += 4) {
                    s0 += src[(size_t)(pc + 0) * 7840];
                    s1 += src[(size_t)(pc + 1) * 7840];
                    s2 += src[(size_t)(pc + 2) * 7840];
                    s3 += src[(size_t)(pc + 3) * 7840];
                }
                v = ((s0 + s1) + (s2 + s3)) * (1.f / 1179.f);
            }
            sM[r * PCI + k] = f2bu(v);
        }
    } else {
        int bx = blockIdx.x - 16;
        b = bx / 19; p0 = (bx % 19) << 6; L = 1179; off = 160;
        conv = (const unsigned short*)pcB;
        const unsigned short* mb = (const unsigned short*)MpW + (size_t)b * 1184 * 160;
        for (int i = threadIdx.x; i < 160 * 64; i += 640) {
            int r = i / 160, k = i - r * 160;
            int p = p0 + r;
            sM[r * PCI + k] = (p < 1179) ? mb[(size_t)p * 160 + k] : (unsigned short)0;
        }
    }
    __syncthreads();
    int lane = threadIdx.x & 63;
    int t = threadIdx.x >> 6;        // wave id == t tile, 0..9
    int n = lane & 15, quad = lane >> 4;
    floatx4 acc[4];
#pragma unroll
    for (int i = 0; i < 4; i++) acc[i] = (floatx4){0.f, 0.f, 0.f, 0.f};
    const unsigned short* W = (const unsigned short*)wattB;
#pragma unroll
    for (int ch = 0; ch < 5; ch++) {
        short8 a = *(const short8*)(W + ((size_t)(t * 16 + n)) * 160 + ch * 32 + quad * 8);
#pragma unroll
        for (int nt = 0; nt < 4; nt++) {
            short8 bb = *(const short8*)(sM + (nt * 16 + n) * PCI + ch * 32 + quad * 8);
            acc[nt] = __builtin_amdgcn_mfma_f32_16x16x32_bf16(a, bb, acc[nt], 0, 0, 0);
        }
    }
    int m0 = quad * 4;
    float vmax[4] = {0.f, 0.f, 0.f, 0.f};
#pragma unroll
    for (int nt = 0; nt < 4; nt++) {
        int p = p0 + nt * 16 + n;
#pragma unroll
        for (int r = 0; r < 4; r++) {
            int o = t * 16 + m0 + r;
            float sig = 1.f / (1.f + __expf(-(acc[nt][r] + attbF[o])));
            float v = 0.f;
            if (p < L) v = u16bf(conv[((size_t)b * 160 + o) * L + p]) * (0.5f + sig);
            vmax[r] = fmaxf(vmax[r], v);
        }
    }
#pragma unroll
    for (int m = 1; m < 16; m <<= 1) {
#pragma unroll
        for (int r = 0; r < 4; r++)
            vmax[r] = fmaxf(vmax[r], __shfl_xor(vmax[r], m, 64));
    }
    if (n == 0) {
#pragma unroll
        for (int r = 0; r < 4; r++)
            atomicMax((unsigned int*)(pair + b * 320 + off + t * 16 + m0 + r),
                      __float_as_uint(vmax[r]));
    }
}

// ---------------- MLP: block-per-output GEMV (R9-proven) ----------------
__global__ __launch_bounds__(256) void fc_block(const float* __restrict__ in,
                                                const void* __restrict__ W,
                                                const float* __restrict__ bias,
                                                float* __restrict__ out,
                                                int IN, int OUT,
                                                const int* __restrict__ flagp) {
    int j = blockIdx.x;
    int w = threadIdx.x >> 6, li = threadIdx.x & 63;
    int nv = IN >> 2;
    const float4* i0 = (const float4*)(in + (size_t)(w * 4 + 0) * IN);
    const float4* i1 = (const float4*)(in + (size_t)(w * 4 + 1) * IN);
    const float4* i2 = (const float4*)(in + (size_t)(w * 4 + 2) * IN);
    const float4* i3 = (const float4*)(in + (size_t)(w * 4 + 3) * IN);
    float p0 = 0.f, p1 = 0.f, p2 = 0.f, p3 = 0.f;
    if (*flagp) {
        const ushort4* w4 = (const ushort4*)((const unsigned short*)W + (size_t)j * IN);
        for (int v = li; v < nv; v += 64) {
            ushort4 u = w4[v];
            float wa = u16bf(u.x), wb = u16bf(u.y), wc = u16bf(u.z), wd = u16bf(u.w);
            float4 x;
            x = i0[v]; p0 += x.x * wa + x.y * wb + x.z * wc + x.w * wd;
            x = i1[v]; p1 += x.x * wa + x.y * wb + x.z * wc + x.w * wd;
            x = i2[v]; p2 += x.x * wa + x.y * wb + x.z * wc + x.w * wd;
            x = i3[v]; p3 += x.x * wa + x.y * wb + x.z * wc + x.w * wd;
        }
    } else {
        const float4* w4 = (const float4*)((const float*)W + (size_t)j * IN);
        for (int v = li; v < nv; v += 64) {
            float4 u = w4[v];
            float4 x;
            x = i0[v]; p0 += x.x * u.x + x.y * u.y + x.z * u.z + x.w * u.w;
            x = i1[v]; p1 += x.x * u.x + x.y * u.y + x.z * u.z + x.w * u.w;
            x = i2[v]; p2 += x.x * u.x + x.y * u.y + x.z * u.z + x.w * u.w;
            x = i3[v]; p3 += x.x * u.x + x.y * u.y + x.z * u.z + x.w * u.w;
        }
    }
#pragma unroll
    for (int m = 1; m < 64; m <<= 1) {
        p0 += __shfl_xor(p0, m, 64);
        p1 += __shfl_xor(p1, m, 64);
        p2 += __shfl_xor(p2, m, 64);
        p3 += __shfl_xor(p3, m, 64);
    }
    if (li == 0) {
        float bj = bias[j];
        float o0 = p0 + bj, o1 = p1 + bj, o2 = p2 + bj, o3 = p3 + bj;
        o0 = o0 > 0.f ? o0 : 0.01f * o0;
        o1 = o1 > 0.f ? o1 : 0.01f * o1;
        o2 = o2 > 0.f ? o2 : 0.01f * o2;
        o3 = o3 > 0.f ? o3 : 0.01f * o3;
        out[(size_t)(w * 4 + 0) * OUT + j] = o0;
        out[(size_t)(w * 4 + 1) * OUT + j] = o1;
        out[(size_t)(w * 4 + 2) * OUT + j] = o2;
        out[(size_t)(w * 4 + 3) * OUT + j] = o3;
    }
}

__global__ __launch_bounds__(256) void out_block(const float* __restrict__ h,
                                                 const void* __restrict__ W,
                                                 const float* __restrict__ biasF,
                                                 void* __restrict__ out,
                                                 const int* __restrict__ flagp) {
    int j = blockIdx.x;
    int w = threadIdx.x >> 6, li = threadIdx.x & 63;
    const int IN = 512, nv = 128;
    const float4* i0 = (const float4*)(h + (size_t)(w * 4 + 0) * IN);
    const float4* i1 = (const float4*)(h + (size_t)(w * 4 + 1) * IN);
    const float4* i2 = (const float4*)(h + (size_t)(w * 4 + 2) * IN);
    const float4* i3 = (const float4*)(h + (size_t)(w * 4 + 3) * IN);
    float p0 = 0.f, p1 = 0.f, p2 = 0.f, p3 = 0.f;
    int flag = *flagp;
    if (flag) {
        const ushort4* w4 = (const ushort4*)((const unsigned short*)W + (size_t)j * IN);
        for (int v = li; v < nv; v += 64) {
            ushort4 u = w4[v];
            float wa = u16bf(u.x), wb = u16bf(u.y), wc = u16bf(u.z), wd = u16bf(u.w);
            float4 x;
            x = i0[v]; p0 += x.x * wa + x.y * wb + x.z * wc + x.w * wd;
            x = i1[v]; p1 += x.x * wa + x.y * wb + x.z * wc + x.w * wd;
            x = i2[v]; p2 += x.x * wa + x.y * wb + x.z * wc + x.w * wd;
            x = i3[v]; p3 += x.x * wa + x.y * wb + x.z * wc + x.w * wd;
        }
    } else {
        const float4* w4 = (const float4*)((const float*)W + (size_t)j * IN);
        for (int v = li; v < nv; v += 64) {
            float4 u = w4[v];
            float4 x;
            x = i0[v]; p0 += x.x * u.x + x.y * u.y + x.z * u.z + x.w * u.w;
            x = i1[v]; p1 += x.x * u.x + x.y * u.y + x.z * u.z + x.w * u.w;
            x = i2[v]; p2 += x.x * u.x + x.y * u.y + x.z * u.z + x.w * u.w;
            x = i3[v]; p3 += x.x * u.x + x.y * u.y + x.z * u.z + x.w * u.w;
        }
    }
#pragma unroll
    for (int m = 1; m < 64; m <<= 1) {
        p0 += __shfl_xor(p0, m, 64);
        p1 += __shfl_xor(p1, m, 64);
        p2 += __shfl_xor(p2, m, 64);
        p3 += __shfl_xor(p3, m, 64);
    }
    if (li == 0) {
        float bj = biasF[j];
        float o0 = p0 + bj, o1 = p1 + bj, o2 = p2 + bj, o3 = p3 + bj;
        if (flag) {
            bf16* ob = (bf16*)out;
            ob[(w * 4 + 0) * 2 + j] = __float2bfloat16(o0);
            ob[(w * 4 + 1) * 2 + j] = __float2bfloat16(o1);
            ob[(w * 4 + 2) * 2 + j] = __float2bfloat16(o2);
            ob[(w * 4 + 3) * 2 + j] = __float2bfloat16(o3);
        } else {
            float* of = (float*)out;
            of[(w * 4 + 0) * 2 + j] = o0;
            of[(w * 4 + 1) * 2 + j] = o1;
            of[(w * 4 + 2) * 2 + j] = o2;
            of[(w * 4 + 3) * 2 + j] = o3;
        }
    }
}

extern "C" void kernel_launch(void* const* d_in, const int* in_sizes, int n_in,
                              void* d_out, int out_size, void* d_ws, size_t ws_size,
                              hipStream_t stream) {
    const int* drug_tok = (const int*)d_in[0];
    const int* prot_tok = (const int*)d_in[1];
    const void* drug_emb = d_in[2];
    const void* prot_emb = d_in[3];
    const void* dW1 = d_in[4];  const void* db1 = d_in[5];
    const void* dW2 = d_in[6];  const void* db2 = d_in[7];
    const void* dW3 = d_in[8];  const void* db3 = d_in[9];
    const void* pW1 = d_in[10]; const void* pb1 = d_in[11];
    const void* pW2 = d_in[12]; const void* pb2 = d_in[13];
    const void* pW3 = d_in[14]; const void* pb3 = d_in[15];
    const void* dattW = d_in[16]; const void* dattb = d_in[17];
    const void* pattW = d_in[18]; const void* pattb = d_in[19];
    const void* attW  = d_in[20]; const void* attb  = d_in[21];
    const void* fc1W = d_in[22]; const void* fc1b = d_in[23];
    const void* fc2W = d_in[24]; const void* fc2b = d_in[25];
    const void* fc3W = d_in[26]; const void* fc3b = d_in[27];
    const void* outW = d_in[28]; const void* outb = d_in[29];

    char* base = (char*)d_ws;
    size_t cur = 0;
    auto alloc = [&](size_t bytes) -> char* {
        char* p = base + cur;
        cur = (cur + bytes + 255) & ~(size_t)255;
        return p;
    };
    int*   flag  = (int*)alloc(256);
    bf16* embDB = (bf16*)alloc(65 * 64 * 2);
    bf16* embPB = (bf16*)alloc(26 * 64 * 2);
    bf16* dW1p = (bf16*)alloc((size_t)4 * 48 * 64 * 2);
    bf16* pW1p = (bf16*)alloc((size_t)4 * 48 * 64 * 2);
    bf16* dW2p = (bf16*)alloc((size_t)6 * 128 * 64 * 2);
    bf16* dW3p = (bf16*)alloc((size_t)8 * 192 * 96 * 2);
    bf16* pW2p = (bf16*)alloc((size_t)8 * 128 * 64 * 2);
    bf16* pW3p = (bf16*)alloc((size_t)12 * 192 * 96 * 2);
    float* db1f = (float*)alloc(40 * 4);
    float* db2f = (float*)alloc(80 * 4);
    float* db3f = (float*)alloc(160 * 4);
    float* pb1f = (float*)alloc(40 * 4);
    float* pb2f = (float*)alloc(80 * 4);
    float* pb3f = (float*)alloc(160 * 4);
    float* dattbF = (float*)alloc(160 * 4);
    float* pattbF = (float*)alloc(160 * 4);
    float* attbF  = (float*)alloc(160 * 4);
    float* fc1bF = (float*)alloc(1024 * 4);
    float* fc2bF = (float*)alloc(1024 * 4);
    float* fc3bF = (float*)alloc(512 * 4);
    float* outbF = (float*)alloc(2 * 4);
    bf16* dattWB = (bf16*)alloc(25600 * 2);
    bf16* pattWB = (bf16*)alloc(25600 * 2);
    bf16* wattB  = (bf16*)alloc(25600 * 2);
    bf16* d1  = (bf16*)alloc((size_t)NB * 40 * 61 * 2);
    bf16* d2  = (bf16*)alloc((size_t)NB * 80 * 56 * 2);
    bf16* dcB = (bf16*)alloc((size_t)NB * 160 * 49 * 2);
    bf16* p1  = (bf16*)alloc((size_t)NB * 40 * 1197 * 2);
    bf16* p2  = (bf16*)alloc((size_t)NB * 80 * 1190 * 2);
    bf16* pcB = (bf16*)alloc((size_t)NB * 160 * 1179 * 2);
    float* datt  = (float*)alloc((size_t)NB * 49 * 160 * 4);
    bf16* pattB = (bf16*)alloc((size_t)NB * 1179 * 160 * 2);
    float* Mdpart = (float*)alloc((size_t)NB * 32 * 49 * 160 * 4);
    bf16* MpW  = (bf16*)alloc((size_t)NB * 1184 * 160 * 2);
    float* pair = (float*)alloc(NB * 320 * 4);
    float* h1 = (float*)alloc(NB * 1024 * 4);
    float* h2 = (float*)alloc(NB * 1024 * 4);
    float* h3 = (float*)alloc(NB * 512 * 4);

    // 1) dtype sniff
    sniff_kernel<<<1, 256, 0, stream>>>((const unsigned short*)fc2W, flag);

    // 2) unified prep: bias cvt + all bf16 packs, one dispatch
    CvtJob cj;
    int si = 0;
    auto add = [&](const void* s, float* d, int n) { cj.src[si] = s; cj.dst[si] = d; cj.n[si] = n; si++; };
    add(db1, db1f, 40); add(db2, db2f, 80); add(db3, db3f, 160);
    add(pb1, pb1f, 40); add(pb2, pb2f, 80); add(pb3, pb3f, 160);
    add(dattb, dattbF, 160); add(pattb, pattbF, 160); add(attb, attbF, 160);
    add(fc1b, fc1bF, 1024); add(fc2b, fc2bF, 1024); add(fc3b, fc3bF, 512);
    add(outb, outbF, 2);
    add(nullptr, pair, NB * 320);
    PackJob pj;
    int pi = 0;
    auto seg = [&](const void* s, bf16* d, int Cout, int CIN, int K, int coP, int CIP) {
        pj.src[pi] = s; pj.dst[pi] = d;
        pj.Cout[pi] = Cout; pj.CIN[pi] = CIN; pj.K[pi] = K; pj.coP[pi] = coP; pj.CIP[pi] = CIP;
        pi++;
    };
    seg(dW1, dW1p, 40, 64, 4, 48, 64);
    seg(pW1, pW1p, 40, 64, 4, 48, 64);
    seg(dW2, dW2p, 80, 40, 6, 128, 64);
    seg(pW2, pW2p, 80, 40, 8, 128, 64);
    seg(dW3, dW3p, 160, 80, 8, 192, 96);
    seg(pW3, pW3p, 160, 80, 12, 192, 96);
    seg(dattW, dattWB, 160, 160, 1, 160, 160);
    seg(pattW, pattWB, 160, 160, 1, 160, 160);
    seg(attW,  wattB,  160, 160, 1, 160, 160);
    seg(drug_emb, embDB, 65, 64, 1, 65, 64);
    seg(prot_emb, embPB, 26, 64, 1, 26, 64);
    prep<<<dim3(864, NSEG + NPK), 256, 0, stream>>>(cj, pj, flag);

    // 3) CNN stacks: conv1, conv2, then conv3 FUSED with att_proj
    conv1_mfma<<<16 + 16 * 19, 256, 0, stream>>>(drug_tok, prot_tok, embDB, embPB,
                                                 dW1p, pW1p, db1f, pb1f, d1, p1);
    conv_dual<6, 8, 40, 2, 5><<<320, 320, 0, stream>>>(
        d1, dW2p, db2f, d2, 61, 56,
        p1, pW2p, pb2f, p2, 1197, 1190, 80, 128);
    conv3_proj<8, 12, 80, 3, 10><<<320, 640, 0, stream>>>(
        d2, dW3p, db3f, dcB, 56, 49,
        p2, pW3p, pb3f, pcB, 1190, 1179, 160, 192,
        dattWB, pattWB, dattbF, pattbF, datt, pattB);

    // 4) fused pairwise relu-means (v9 structure)
    mean_fused<<<16 * 32, 640, 0, stream>>>(datt, pattB, MpW, Mdpart);

    // 5) fused attW-GEMM + sigmoid + scale + maxpool (+ inline Md reduction)
    att_sig_mfma<<<320, 640, 0, stream>>>(Mdpart, MpW, wattB, attbF, dcB, pcB, pair);

    // 6) MLP head (block-per-output GEMV)
    fc_block<<<1024, 256, 0, stream>>>(pair, fc1W, fc1bF, h1, 320, 1024, flag);
    fc_block<<<1024, 256, 0, stream>>>(h1, fc2W, fc2bF, h2, 1024, 1024, flag);
    fc_block<<<512, 256, 0, stream>>>(h2, fc3W, fc3bF, h3, 1024, 512, flag);
    out_block<<<2, 256, 0, stream>>>(h3, outW, outbF, d_out, flag);
}

// Round 9
// 238.917 us; speedup vs baseline: 1.0120x; 1.0120x over previous
//
#include <hip/hip_runtime.h>
#include <hip/hip_bf16.h>

typedef __hip_bfloat16 bf16;
typedef __attribute__((ext_vector_type(8))) short short8;
typedef __attribute__((ext_vector_type(4))) float floatx4;

#define NB 16

// drug conv chain:  L 64 ->61(K4,C40) ->56(K6,C80) ->49(K8,C160)   (d1 rows padded to 62)
// prot conv chain:  L 1200 ->1197(K4,C40) ->1190(K8,C80) ->1179(K12,C160)  (p1 rows padded to 1198)

__device__ __forceinline__ float b2f(bf16 x) { return __bfloat162float(x); }
__device__ __forceinline__ float u16bf(unsigned short u) {
    return __uint_as_float(((unsigned)u) << 16);
}
__device__ __forceinline__ unsigned short f2bu(float v) {
    union { bf16 h; unsigned short u; } cv;
    cv.h = __float2bfloat16(v);
    return cv.u;
}

// ---------------- dtype sniffer (R4-proven) ----------------
__global__ void sniff_kernel(const unsigned short* __restrict__ w, int* __restrict__ flag) {
    __shared__ int cnt;
    if (threadIdx.x == 0) cnt = 0;
    __syncthreads();
    int hits = 0;
    for (int s = 0; s < 4; s++) {
        unsigned short u = w[(threadIdx.x * 4 + s) * 2];
        float v = fabsf(u16bf(u));
        if (v > 1e-6f && v < 2.0f) hits++;
    }
    atomicAdd(&cnt, hits);
    __syncthreads();
    if (threadIdx.x == 0) *flag = (cnt > 512) ? 1 : 0;
}

// ---------------- unified prep: flattened 1D (v12) ----------------
// v11's (864,25) grid launched 21.6k blocks, ~90% empty. v12: one 1D grid over
// the concatenated element range with an unrolled 25-seg offset search.
#define NSEG 14
struct CvtJob {
    const void* src[NSEG];
    float* dst[NSEG];
};
#define NPK 11
struct PackJob {
    const void* src[NPK];
    bf16* dst[NPK];
    short Cout[NPK], CIN[NPK], K[NPK], coP[NPK], CIP[NPK];
};
struct PrepOff { int off[NSEG + NPK + 1]; };

__global__ void prep(CvtJob cj, PackJob pj, PrepOff po, const int* __restrict__ flagp) {
    int g = blockIdx.x * 256 + threadIdx.x;
    if (g >= po.off[NSEG + NPK]) return;
    int s = 0;
#pragma unroll
    for (int t = 1; t < NSEG + NPK; t++)
        if (g >= po.off[t]) s = t;
    int i = g - po.off[s];
    if (s < NSEG) {
        const void* sp = cj.src[s];
        if (sp == nullptr) { cj.dst[s][i] = 0.f; return; }
        cj.dst[s][i] = (*flagp) ? b2f(((const bf16*)sp)[i]) : ((const float*)sp)[i];
    } else {
        int p = s - NSEG;
        int Cout = pj.Cout[p], CIN = pj.CIN[p], K = pj.K[p];
        int coP = pj.coP[p], CIP = pj.CIP[p];
        (void)K;
        int ci = i % CIP;
        int t = i / CIP;
        int co = t % coP;
        int k = t / coP;
        float v = 0.f;
        if (co < Cout && ci < CIN) {
            int si = (co * CIN + ci) * pj.K[p] + k;
            v = (*flagp) ? b2f(((const bf16*)pj.src[p])[si]) : ((const float*)pj.src[p])[si];
        }
        pj.dst[p][i] = __float2bfloat16(v);
    }
}

// ---------------- conv via MFMA implicit GEMM: shared body ----------------
// v12: staging vectorized -- short8 loads along L (8x fewer global ops). Lstride
// decouples row pitch from Lin so odd-length rows are padded even (4B-aligned
// vector loads). Wave w owns ct=w (v10 fold-y).
template <int K, int CIN, int CHUNKS, int NW>
__device__ __forceinline__ void conv_body(unsigned short* xT,
                                          const unsigned short* xb,
                                          const unsigned short* wbase,
                                          const float* __restrict__ bias,
                                          bf16* __restrict__ y,
                                          int b, int Lin, int Lstride, int Lout,
                                          int Cout, int coP, int l0) {
    const int CIP = CHUNKS * 32;
    const int PCI = CIP + 8;
    const int TLX = 64 + K - 1;
    const int LV = (TLX + 7) >> 3;
    for (int i = threadIdx.x; i < CIP * LV; i += NW * 64) {
        int ci = i / LV, lv = (i - ci * LV) << 3;
        if (ci < CIN && lv + 8 <= TLX && l0 + lv + 8 <= Lin) {
            short8 v = *(const short8*)(xb + ci * Lstride + l0 + lv);
#pragma unroll
            for (int j = 0; j < 8; j++) xT[(lv + j) * PCI + ci] = (unsigned short)v[j];
        } else {
            for (int j = 0; j < 8; j++) {
                int l = lv + j;
                if (l >= TLX) break;
                int gl = l0 + l;
                xT[l * PCI + ci] = (ci < CIN && gl < Lin) ? xb[ci * Lstride + gl]
                                                          : (unsigned short)0;
            }
        }
    }
    __syncthreads();
    int lane = threadIdx.x & 63;
    int ct = threadIdx.x >> 6;       // wave id == ct tile
    int n = lane & 15, quad = lane >> 4;
    floatx4 acc[4];
#pragma unroll
    for (int i = 0; i < 4; i++) acc[i] = (floatx4){0.f, 0.f, 0.f, 0.f};
#pragma unroll
    for (int k = 0; k < K; k++) {
#pragma unroll
        for (int ch = 0; ch < CHUNKS; ch++) {
            short8 a = *(const short8*)(wbase +
                        ((size_t)(k * coP + ct * 16 + n)) * CIP + ch * 32 + quad * 8);
#pragma unroll
            for (int nt = 0; nt < 4; nt++) {
                short8 bb = *(const short8*)(xT + (nt * 16 + n + k) * PCI + ch * 32 + quad * 8);
                acc[nt] = __builtin_amdgcn_mfma_f32_16x16x32_bf16(a, bb, acc[nt], 0, 0, 0);
            }
        }
    }
    int m0 = quad * 4;
#pragma unroll
    for (int nt = 0; nt < 4; nt++) {
        int l = l0 + nt * 16 + n;
        if (l >= Lout) continue;
#pragma unroll
        for (int r = 0; r < 4; r++) {
            int co = ct * 16 + m0 + r;
            if (co < Cout)
                y[((size_t)b * Cout + co) * Lout + l] =
                    __float2bfloat16(fmaxf(acc[nt][r] + bias[co], 0.f));
        }
    }
}

// merged drug+prot conv (layer 2), NW waves = NW ct-tiles
template <int KD, int KP, int CIN, int CHUNKS, int NW>
__global__ __launch_bounds__(NW * 64) void conv_dual(const bf16* __restrict__ xd,
                                                 const bf16* __restrict__ Wpd,
                                                 const float* __restrict__ bd,
                                                 bf16* __restrict__ yd,
                                                 int LinD, int LsD, int LoutD,
                                                 const bf16* __restrict__ xp,
                                                 const bf16* __restrict__ Wpp,
                                                 const float* __restrict__ bp,
                                                 bf16* __restrict__ yp,
                                                 int LinP, int LsP, int LoutP,
                                                 int Cout, int coP) {
    const int CIP = CHUNKS * 32;
    const int PCI = CIP + 8;
    const int TLXMAX = 64 + KP - 1;   // KP >= KD
    __shared__ __align__(16) unsigned short xT[TLXMAX * PCI];
    if (blockIdx.x < 16) {
        int b = blockIdx.x;
        conv_body<KD, CIN, CHUNKS, NW>(xT, (const unsigned short*)xd + (size_t)b * CIN * LsD,
                                   (const unsigned short*)Wpd, bd, yd, b, LinD, LsD, LoutD,
                                   Cout, coP, 0);
    } else {
        int bx = blockIdx.x - 16;
        int b = bx / 19, l0 = (bx % 19) << 6;
        conv_body<KP, CIN, CHUNKS, NW>(xT, (const unsigned short*)xp + (size_t)b * CIN * LsP,
                                   (const unsigned short*)Wpp, bp, yp, b, LinP, LsP, LoutP,
                                   Cout, coP, l0);
    }
}

// ---------------- conv3 + att_proj FUSED (v11) with v12 vectorized staging ----------------
template <int K, int CIN, int CHUNKS, int NW>
__device__ __forceinline__ void conv_proj_phase(unsigned short* xT, unsigned short* xP,
                                                const unsigned short* xb,
                                                const unsigned short* wbase,
                                                const float* __restrict__ bias,
                                                unsigned short* __restrict__ y,
                                                int b, int Lin, int Lout,
                                                int Cout, int coP, int l0) {
    const int CIP = CHUNKS * 32;
    const int PCI = CIP + 8;
    const int TLX = 64 + K - 1;
    const int LV = (TLX + 7) >> 3;
    for (int i = threadIdx.x; i < CIP * LV; i += NW * 64) {
        int ci = i / LV, lv = (i - ci * LV) << 3;
        if (ci < CIN && lv + 8 <= TLX && l0 + lv + 8 <= Lin) {
            short8 v = *(const short8*)(xb + ci * Lin + l0 + lv);
#pragma unroll
            for (int j = 0; j < 8; j++) xT[(lv + j) * PCI + ci] = (unsigned short)v[j];
        } else {
            for (int j = 0; j < 8; j++) {
                int l = lv + j;
                if (l >= TLX) break;
                int gl = l0 + l;
                xT[l * PCI + ci] = (ci < CIN && gl < Lin) ? xb[ci * Lin + gl]
                                                          : (unsigned short)0;
            }
        }
    }
    __syncthreads();
    int lane = threadIdx.x & 63;
    int ct = threadIdx.x >> 6;
    int n = lane & 15, quad = lane >> 4;
    floatx4 acc[4];
#pragma unroll
    for (int i = 0; i < 4; i++) acc[i] = (floatx4){0.f, 0.f, 0.f, 0.f};
#pragma unroll
    for (int k = 0; k < K; k++) {
#pragma unroll
        for (int ch = 0; ch < CHUNKS; ch++) {
            short8 a = *(const short8*)(wbase +
                        ((size_t)(k * coP + ct * 16 + n)) * CIP + ch * 32 + quad * 8);
#pragma unroll
            for (int nt = 0; nt < 4; nt++) {
                short8 bb = *(const short8*)(xT + (nt * 16 + n + k) * PCI + ch * 32 + quad * 8);
                acc[nt] = __builtin_amdgcn_mfma_f32_16x16x32_bf16(a, bb, acc[nt], 0, 0, 0);
            }
        }
    }
    int m0 = quad * 4;
#pragma unroll
    for (int nt = 0; nt < 4; nt++) {
        int ll = nt * 16 + n;
        int l = l0 + ll;
#pragma unroll
        for (int r = 0; r < 4; r++) {
            int co = ct * 16 + m0 + r;
            float val = (l < Lout) ? fmaxf(acc[nt][r] + bias[co], 0.f) : 0.f;
            unsigned short u = f2bu(val);
            xP[ll * 168 + co] = u;                          // proj input tile
            if (l < Lout) y[((size_t)b * Cout + co) * Lout + l] = u;  // for att_sig
        }
    }
}

template <int KD, int KP, int CIN, int CHUNKS, int NW>
__global__ __launch_bounds__(NW * 64) void conv3_proj(
        const bf16* __restrict__ xd, const bf16* __restrict__ Wpd,
        const float* __restrict__ bd, bf16* __restrict__ yd, int LinD, int LoutD,
        const bf16* __restrict__ xp, const bf16* __restrict__ Wpp,
        const float* __restrict__ bp, bf16* __restrict__ yp, int LinP, int LoutP,
        int Cout, int coP,
        const bf16* __restrict__ dWB, const bf16* __restrict__ pWB,
        const float* __restrict__ dbF, const float* __restrict__ pbF,
        float* __restrict__ datt, bf16* __restrict__ pattB) {
    const int CIP = CHUNKS * 32;
    const int PCI = CIP + 8;
    const int TLXMAX = 64 + KP - 1;
    __shared__ __align__(16) unsigned short xT[TLXMAX * PCI];
    __shared__ __align__(16) unsigned short xP[64 * 168];
    bool isD = blockIdx.x < 16;
    int b, l0, L;
    if (isD) {
        b = blockIdx.x; l0 = 0; L = LoutD;
        conv_proj_phase<KD, CIN, CHUNKS, NW>(xT, xP,
            (const unsigned short*)xd + (size_t)b * CIN * LinD,
            (const unsigned short*)Wpd, bd, (unsigned short*)yd, b, LinD, LoutD, Cout, coP, 0);
    } else {
        int bx = blockIdx.x - 16;
        b = bx / 19; l0 = (bx % 19) << 6; L = LoutP;
        conv_proj_phase<KP, CIN, CHUNKS, NW>(xT, xP,
            (const unsigned short*)xp + (size_t)b * CIN * LinP,
            (const unsigned short*)Wpp, bp, (unsigned short*)yp, b, LinP, LoutP, Cout, coP, l0);
    }
    __syncthreads();
    // projection phase: wave t owns output tile t (0..NW-1), reads xP
    int lane = threadIdx.x & 63;
    int t = threadIdx.x >> 6;
    int n = lane & 15, quad = lane >> 4;
    const unsigned short* W = (const unsigned short*)(isD ? dWB : pWB);
    const float* pbias = isD ? dbF : pbF;
    floatx4 acc[4];
#pragma unroll
    for (int i = 0; i < 4; i++) acc[i] = (floatx4){0.f, 0.f, 0.f, 0.f};
#pragma unroll
    for (int ch = 0; ch < 5; ch++) {
        short8 a = *(const short8*)(W + ((size_t)(t * 16 + n)) * 160 + ch * 32 + quad * 8);
#pragma unroll
        for (int nt = 0; nt < 4; nt++) {
            short8 bb = *(const short8*)(xP + (nt * 16 + n) * 168 + ch * 32 + quad * 8);
            acc[nt] = __builtin_amdgcn_mfma_f32_16x16x32_bf16(a, bb, acc[nt], 0, 0, 0);
        }
    }
    int m0 = quad * 4;
    int o0 = t * 16 + m0;
#pragma unroll
    for (int nt = 0; nt < 4; nt++) {
        int l = l0 + nt * 16 + n;
        if (l >= L) continue;
        if (isD) {
            float4 v;
            v.x = acc[nt][0] + pbias[o0 + 0];
            v.y = acc[nt][1] + pbias[o0 + 1];
            v.z = acc[nt][2] + pbias[o0 + 2];
            v.w = acc[nt][3] + pbias[o0 + 3];
            *(float4*)(datt + ((size_t)b * 49 + l) * 160 + o0) = v;
        } else {
            ushort4 u;
            u.x = f2bu(acc[nt][0] + pbias[o0 + 0]);
            u.y = f2bu(acc[nt][1] + pbias[o0 + 1]);
            u.z = f2bu(acc[nt][2] + pbias[o0 + 2]);
            u.w = f2bu(acc[nt][3] + pbias[o0 + 3]);
            *(ushort4*)((unsigned short*)pattB + ((size_t)b * 1179 + l) * 160 + o0) = u;
        }
    }
}

// ---------------- conv1 via MFMA with embedding-gather staging ----------------
// v12: gather staging vectorized -- per (l, ci8) one short8 emb-row copy (both
// sides 16B-aligned); 536 vec-iters vs 4288 scalar. Output rows padded (62/1198).
__global__ __launch_bounds__(256) void conv1_mfma(const int* __restrict__ dtok,
                                                  const int* __restrict__ ptok,
                                                  const bf16* __restrict__ embDB,
                                                  const bf16* __restrict__ embPB,
                                                  const bf16* __restrict__ dW1p,
                                                  const bf16* __restrict__ pW1p,
                                                  const float* __restrict__ db1f,
                                                  const float* __restrict__ pb1f,
                                                  bf16* __restrict__ d1,
                                                  bf16* __restrict__ p1) {
    const int K = 4, CIP = 64, PCI = 72, TLX = 67, coP = 48, Cout = 40;
    __shared__ __align__(16) unsigned short xT[TLX * PCI];
    __shared__ int stok[TLX];
    bool isD = blockIdx.x < 16;
    int b, l0, Lin, Lout, Ostride;
    const int* tok; const unsigned short* embB; const unsigned short* Wp;
    const float* bias; bf16* y;
    if (isD) {
        b = blockIdx.x; l0 = 0; Lin = 64; Lout = 61; Ostride = 62;
        tok = dtok; embB = (const unsigned short*)embDB;
        Wp = (const unsigned short*)dW1p; bias = db1f; y = d1;
    } else {
        int bx = blockIdx.x - 16;
        b = bx / 19; l0 = (bx % 19) << 6; Lin = 1200; Lout = 1197; Ostride = 1198;
        tok = ptok; embB = (const unsigned short*)embPB;
        Wp = (const unsigned short*)pW1p; bias = pb1f; y = p1;
    }
    if (threadIdx.x < TLX) {
        int l = l0 + threadIdx.x;
        stok[threadIdx.x] = (l < Lin) ? tok[b * Lin + l] : -1;
    }
    __syncthreads();
    for (int i = threadIdx.x; i < TLX * 8; i += 256) {
        int l = i >> 3, c8 = (i & 7) << 3;
        int t = stok[l];
        short8 v = (short8){0, 0, 0, 0, 0, 0, 0, 0};
        if (t >= 0) v = *(const short8*)(embB + t * 64 + c8);
        *(short8*)(xT + l * PCI + c8) = v;
    }
    __syncthreads();
    int lane = threadIdx.x & 63;
    int w = threadIdx.x >> 6;
    int n = lane & 15, quad = lane >> 4;
    if (w >= 3) return;
    floatx4 acc[4];
#pragma unroll
    for (int i = 0; i < 4; i++) acc[i] = (floatx4){0.f, 0.f, 0.f, 0.f};
#pragma unroll
    for (int k = 0; k < K; k++) {
#pragma unroll
        for (int ch = 0; ch < 2; ch++) {
            short8 a = *(const short8*)(Wp +
                        ((size_t)(k * coP + w * 16 + n)) * CIP + ch * 32 + quad * 8);
#pragma unroll
            for (int nt = 0; nt < 4; nt++) {
                short8 bb = *(const short8*)(xT + (nt * 16 + n + k) * PCI + ch * 32 + quad * 8);
                acc[nt] = __builtin_amdgcn_mfma_f32_16x16x32_bf16(a, bb, acc[nt], 0, 0, 0);
            }
        }
    }
    int m0 = quad * 4;
#pragma unroll
    for (int nt = 0; nt < 4; nt++) {
        int l = l0 + nt * 16 + n;
        if (l >= Lout) continue;
#pragma unroll
        for (int r = 0; r < 4; r++) {
            int co = w * 16 + m0 + r;
            if (co < Cout)
                y[((size_t)b * Cout + co) * Ostride + l] =
                    __float2bfloat16(fmaxf(acc[nt][r] + bias[co], 0.f));
        }
    }
}

// ---------------- fused means v9: 4-way d-split for 2x TLP (proven) ----------------
__global__ __launch_bounds__(640) void mean_fused(const float* __restrict__ datt,
                                                  const bf16* __restrict__ patt,
                                                  bf16* __restrict__ MpW,
                                                  float* __restrict__ Mdpart) {
    __shared__ __align__(16) unsigned short sp[37 * 160];
    int tid = threadIdx.x;
    int b = blockIdx.x >> 5;          // / 32
    int pc = blockIdx.x & 31;
    int p0 = pc * 37;                 // 32 chunks of 37 cover 1179 (last: 32 valid)
    int pmax = 1179 - p0;
    if (pmax > 37) pmax = 37;
    // stage p-tile (coalesced short8): sp[pi][k] = patt[b][p0+pi][k]
    {
        const short8* src = (const short8*)((const unsigned short*)patt +
                                            ((size_t)b * 1179 + p0) * 160);
        short8* dst = (short8*)sp;
        int n8 = (pmax * 160) >> 3;   // multiple of 20, exact
        for (int v = tid; v < n8; v += 640) dst[v] = src[v];
    }
    int h = tid & 3;
    int k = tid >> 2;                 // 0..159
    int d0 = h * 13;                  // 0,13,26,39
    int nd = (h == 3) ? 10 : 13;      // 13+13+13+10 = 49
    const float* drow = datt + (size_t)b * 49 * 160 + k;
    float dv[13], md[13];
#pragma unroll
    for (int i = 0; i < 13; i++) {
        // pad slots: dv=-1e30 -> relu(dv+pv)==0, contributes nothing
        dv[i] = (i < nd) ? drow[(d0 + i) * 160] : -1e30f;
        md[i] = 0.f;
    }
    __syncthreads();
    unsigned short* mp = (unsigned short*)MpW + ((size_t)b * 1184 + p0) * 160 + k;
#pragma unroll 2
    for (int pi = 0; pi < pmax; pi++) {
        float pv = u16bf(sp[pi * 160 + k]);
        float s0 = 0.f, s1 = 0.f, s2 = 0.f, s3 = 0.f;
#pragma unroll
        for (int g = 0; g < 3; g++) {
            float r0 = fmaxf(dv[g * 4 + 0] + pv, 0.f);
            float r1 = fmaxf(dv[g * 4 + 1] + pv, 0.f);
            float r2 = fmaxf(dv[g * 4 + 2] + pv, 0.f);
            float r3 = fmaxf(dv[g * 4 + 3] + pv, 0.f);
            md[g * 4 + 0] += r0; s0 += r0;
            md[g * 4 + 1] += r1; s1 += r1;
            md[g * 4 + 2] += r2; s2 += r2;
            md[g * 4 + 3] += r3; s3 += r3;
        }
        {
            float r = fmaxf(dv[12] + pv, 0.f);
            md[12] += r; s0 += r;
        }
        float s = (s0 + s1) + (s2 + s3);
        s += __shfl_xor(s, 1, 64);    // combine 4 d-quarters (lanes 4k..4k+3)
        s += __shfl_xor(s, 2, 64);
        if (h == 0) mp[(size_t)pi * 160] = f2bu(s * (1.f / 49.f));
    }
    // streaming partial store: [b][pc][d][k], wave-coalesced runs, no RMW
    float* op = Mdpart + (((size_t)b * 32 + pc) * 49) * 160 + k;
#pragma unroll
    for (int i = 0; i < 13; i++)
        if (i < nd) op[(d0 + i) * 160] = md[i];
}

// ---------------- att_sig via MFMA + fused sigmoid/scale/maxpool (v11: inline Md reduce) ----------------
__global__ __launch_bounds__(640) void att_sig_mfma(const float* __restrict__ Mdpart,
                                                    const bf16* __restrict__ MpW,
                                                    const bf16* __restrict__ wattB,
                                                    const float* __restrict__ attbF,
                                                    const bf16* __restrict__ dcB,
                                                    const bf16* __restrict__ pcB,
                                                    float* __restrict__ pair) {
    const int PCI = 168;
    __shared__ __align__(16) unsigned short sM[64 * PCI];
    bool isD = blockIdx.x < 16;
    int b, p0, L, off;
    const unsigned short* conv;
    if (isD) {
        b = blockIdx.x; p0 = 0; L = 49; off = 0; conv = (const unsigned short*)dcB;
        const float* mdp = Mdpart + (size_t)b * 32 * 49 * 160;
        for (int i = threadIdx.x; i < 160 * 64; i += 640) {
            int r = i / 160, k = i - r * 160;
            float v = 0.f;
            if (r < 49) {
                const float* src = mdp + r * 160 + k;
                float s0 = 0.f, s1 = 0.f, s2 = 0.f, s3 = 0.f;
#pragma unroll
                for (int pc = 0; pc < 32; pc += 4) {
                    s0 += src[(size_t)(pc + 0) * 7840];
                    s1 += src[(size_t)(pc + 1) * 7840];
                    s2 += src[(size_t)(pc + 2) * 7840];
                    s3 += src[(size_t)(pc + 3) * 7840];
                }
                v = ((s0 + s1) + (s2 + s3)) * (1.f / 1179.f);
            }
            sM[r * PCI + k] = f2bu(v);
        }
    } else {
        int bx = blockIdx.x - 16;
        b = bx / 19; p0 = (bx % 19) << 6; L = 1179; off = 160;
        conv = (const unsigned short*)pcB;
        const unsigned short* mb = (const unsigned short*)MpW + (size_t)b * 1184 * 160;
        for (int i = threadIdx.x; i < 160 * 64; i += 640) {
            int r = i / 160, k = i - r * 160;
            int p = p0 + r;
            sM[r * PCI + k] = (p < 1179) ? mb[(size_t)p * 160 + k] : (unsigned short)0;
        }
    }
    __syncthreads();
    int lane = threadIdx.x & 63;
    int t = threadIdx.x >> 6;        // wave id == t tile, 0..9
    int n = lane & 15, quad = lane >> 4;
    floatx4 acc[4];
#pragma unroll
    for (int i = 0; i < 4; i++) acc[i] = (floatx4){0.f, 0.f, 0.f, 0.f};
    const unsigned short* W = (const unsigned short*)wattB;
#pragma unroll
    for (int ch = 0; ch < 5; ch++) {
        short8 a = *(const short8*)(W + ((size_t)(t * 16 + n)) * 160 + ch * 32 + quad * 8);
#pragma unroll
        for (int nt = 0; nt < 4; nt++) {
            short8 bb = *(const short8*)(sM + (nt * 16 + n) * PCI + ch * 32 + quad * 8);
            acc[nt] = __builtin_amdgcn_mfma_f32_16x16x32_bf16(a, bb, acc[nt], 0, 0, 0);
        }
    }
    int m0 = quad * 4;
    float vmax[4] = {0.f, 0.f, 0.f, 0.f};
#pragma unroll
    for (int nt = 0; nt < 4; nt++) {
        int p = p0 + nt * 16 + n;
#pragma unroll
        for (int r = 0; r < 4; r++) {
            int o = t * 16 + m0 + r;
            float sig = 1.f / (1.f + __expf(-(acc[nt][r] + attbF[o])));
            float v = 0.f;
            if (p < L) v = u16bf(conv[((size_t)b * 160 + o) * L + p]) * (0.5f + sig);
            vmax[r] = fmaxf(vmax[r], v);
        }
    }
#pragma unroll
    for (int m = 1; m < 16; m <<= 1) {
#pragma unroll
        for (int r = 0; r < 4; r++)
            vmax[r] = fmaxf(vmax[r], __shfl_xor(vmax[r], m, 64));
    }
    if (n == 0) {
#pragma unroll
        for (int r = 0; r < 4; r++)
            atomicMax((unsigned int*)(pair + b * 320 + off + t * 16 + m0 + r),
                      __float_as_uint(vmax[r]));
    }
}

// ---------------- MLP: block-per-output GEMV (R9-proven) ----------------
__global__ __launch_bounds__(256) void fc_block(const float* __restrict__ in,
                                                const void* __restrict__ W,
                                                const float* __restrict__ bias,
                                                float* __restrict__ out,
                                                int IN, int OUT,
                                                const int* __restrict__ flagp) {
    int j = blockIdx.x;
    int w = threadIdx.x >> 6, li = threadIdx.x & 63;
    int nv = IN >> 2;
    const float4* i0 = (const float4*)(in + (size_t)(w * 4 + 0) * IN);
    const float4* i1 = (const float4*)(in + (size_t)(w * 4 + 1) * IN);
    const float4* i2 = (const float4*)(in + (size_t)(w * 4 + 2) * IN);
    const float4* i3 = (const float4*)(in + (size_t)(w * 4 + 3) * IN);
    float p0 = 0.f, p1 = 0.f, p2 = 0.f, p3 = 0.f;
    if (*flagp) {
        const ushort4* w4 = (const ushort4*)((const unsigned short*)W + (size_t)j * IN);
        for (int v = li; v < nv; v += 64) {
            ushort4 u = w4[v];
            float wa = u16bf(u.x), wb = u16bf(u.y), wc = u16bf(u.z), wd = u16bf(u.w);
            float4 x;
            x = i0[v]; p0 += x.x * wa + x.y * wb + x.z * wc + x.w * wd;
            x = i1[v]; p1 += x.x * wa + x.y * wb + x.z * wc + x.w * wd;
            x = i2[v]; p2 += x.x * wa + x.y * wb + x.z * wc + x.w * wd;
            x = i3[v]; p3 += x.x * wa + x.y * wb + x.z * wc + x.w * wd;
        }
    } else {
        const float4* w4 = (const float4*)((const float*)W + (size_t)j * IN);
        for (int v = li; v < nv; v += 64) {
            float4 u = w4[v];
            float4 x;
            x = i0[v]; p0 += x.x * u.x + x.y * u.y + x.z * u.z + x.w * u.w;
            x = i1[v]; p1 += x.x * u.x + x.y * u.y + x.z * u.z + x.w * u.w;
            x = i2[v]; p2 += x.x * u.x + x.y * u.y + x.z * u.z + x.w * u.w;
            x = i3[v]; p3 += x.x * u.x + x.y * u.y + x.z * u.z + x.w * u.w;
        }
    }
#pragma unroll
    for (int m = 1; m < 64; m <<= 1) {
        p0 += __shfl_xor(p0, m, 64);
        p1 += __shfl_xor(p1, m, 64);
        p2 += __shfl_xor(p2, m, 64);
        p3 += __shfl_xor(p3, m, 64);
    }
    if (li == 0) {
        float bj = bias[j];
        float o0 = p0 + bj, o1 = p1 + bj, o2 = p2 + bj, o3 = p3 + bj;
        o0 = o0 > 0.f ? o0 : 0.01f * o0;
        o1 = o1 > 0.f ? o1 : 0.01f * o1;
        o2 = o2 > 0.f ? o2 : 0.01f * o2;
        o3 = o3 > 0.f ? o3 : 0.01f * o3;
        out[(size_t)(w * 4 + 0) * OUT + j] = o0;
        out[(size_t)(w * 4 + 1) * OUT + j] = o1;
        out[(size_t)(w * 4 + 2) * OUT + j] = o2;
        out[(size_t)(w * 4 + 3) * OUT + j] = o3;
    }
}

__global__ __launch_bounds__(256) void out_block(const float* __restrict__ h,
                                                 const void* __restrict__ W,
                                                 const float* __restrict__ biasF,
                                                 void* __restrict__ out,
                                                 const int* __restrict__ flagp) {
    int j = blockIdx.x;
    int w = threadIdx.x >> 6, li = threadIdx.x & 63;
    const int IN = 512, nv = 128;
    const float4* i0 = (const float4*)(h + (size_t)(w * 4 + 0) * IN);
    const float4* i1 = (const float4*)(h + (size_t)(w * 4 + 1) * IN);
    const float4* i2 = (const float4*)(h + (size_t)(w * 4 + 2) * IN);
    const float4* i3 = (const float4*)(h + (size_t)(w * 4 + 3) * IN);
    float p0 = 0.f, p1 = 0.f, p2 = 0.f, p3 = 0.f;
    int flag = *flagp;
    if (flag) {
        const ushort4* w4 = (const ushort4*)((const unsigned short*)W + (size_t)j * IN);
        for (int v = li; v < nv; v += 64) {
            ushort4 u = w4[v];
            float wa = u16bf(u.x), wb = u16bf(u.y), wc = u16bf(u.z), wd = u16bf(u.w);
            float4 x;
            x = i0[v]; p0 += x.x * wa + x.y * wb + x.z * wc + x.w * wd;
            x = i1[v]; p1 += x.x * wa + x.y * wb + x.z * wc + x.w * wd;
            x = i2[v]; p2 += x.x * wa + x.y * wb + x.z * wc + x.w * wd;
            x = i3[v]; p3 += x.x * wa + x.y * wb + x.z * wc + x.w * wd;
        }
    } else {
        const float4* w4 = (const float4*)((const float*)W + (size_t)j * IN);
        for (int v = li; v < nv; v += 64) {
            float4 u = w4[v];
            float4 x;
            x = i0[v]; p0 += x.x * u.x + x.y * u.y + x.z * u.z + x.w * u.w;
            x = i1[v]; p1 += x.x * u.x + x.y * u.y + x.z * u.z + x.w * u.w;
            x = i2[v]; p2 += x.x * u.x + x.y * u.y + x.z * u.z + x.w * u.w;
            x = i3[v]; p3 += x.x * u.x + x.y * u.y + x.z * u.z + x.w * u.w;
        }
    }
#pragma unroll
    for (int m = 1; m < 64; m <<= 1) {
        p0 += __shfl_xor(p0, m, 64);
        p1 += __shfl_xor(p1, m, 64);
        p2 += __shfl_xor(p2, m, 64);
        p3 += __shfl_xor(p3, m, 64);
    }
    if (li == 0) {
        float bj = biasF[j];
        float o0 = p0 + bj, o1 = p1 + bj, o2 = p2 + bj, o3 = p3 + bj;
        if (flag) {
            bf16* ob = (bf16*)out;
            ob[(w * 4 + 0) * 2 + j] = __float2bfloat16(o0);
            ob[(w * 4 + 1) * 2 + j] = __float2bfloat16(o1);
            ob[(w * 4 + 2) * 2 + j] = __float2bfloat16(o2);
            ob[(w * 4 + 3) * 2 + j] = __float2bfloat16(o3);
        } else {
            float* of = (float*)out;
            of[(w * 4 + 0) * 2 + j] = o0;
            of[(w * 4 + 1) * 2 + j] = o1;
            of[(w * 4 + 2) * 2 + j] = o2;
            of[(w * 4 + 3) * 2 + j] = o3;
        }
    }
}

extern "C" void kernel_launch(void* const* d_in, const int* in_sizes, int n_in,
                              void* d_out, int out_size, void* d_ws, size_t ws_size,
                              hipStream_t stream) {
    const int* drug_tok = (const int*)d_in[0];
    const int* prot_tok = (const int*)d_in[1];
    const void* drug_emb = d_in[2];
    const void* prot_emb = d_in[3];
    const void* dW1 = d_in[4];  const void* db1 = d_in[5];
    const void* dW2 = d_in[6];  const void* db2 = d_in[7];
    const void* dW3 = d_in[8];  const void* db3 = d_in[9];
    const void* pW1 = d_in[10]; const void* pb1 = d_in[11];
    const void* pW2 = d_in[12]; const void* pb2 = d_in[13];
    const void* pW3 = d_in[14]; const void* pb3 = d_in[15];
    const void* dattW = d_in[16]; const void* dattb = d_in[17];
    const void* pattW = d_in[18]; const void* pattb = d_in[19];
    const void* attW  = d_in[20]; const void* attb  = d_in[21];
    const void* fc1W = d_in[22]; const void* fc1b = d_in[23];
    const void* fc2W = d_in[24]; const void* fc2b = d_in[25];
    const void* fc3W = d_in[26]; const void* fc3b = d_in[27];
    const void* outW = d_in[28]; const void* outb = d_in[29];

    char* base = (char*)d_ws;
    size_t cur = 0;
    auto alloc = [&](size_t bytes) -> char* {
        char* p = base + cur;
        cur = (cur + bytes + 255) & ~(size_t)255;
        return p;
    };
    int*   flag  = (int*)alloc(256);
    bf16* embDB = (bf16*)alloc(65 * 64 * 2);
    bf16* embPB = (bf16*)alloc(26 * 64 * 2);
    bf16* dW1p = (bf16*)alloc((size_t)4 * 48 * 64 * 2);
    bf16* pW1p = (bf16*)alloc((size_t)4 * 48 * 64 * 2);
    bf16* dW2p = (bf16*)alloc((size_t)6 * 128 * 64 * 2);
    bf16* dW3p = (bf16*)alloc((size_t)8 * 192 * 96 * 2);
    bf16* pW2p = (bf16*)alloc((size_t)8 * 128 * 64 * 2);
    bf16* pW3p = (bf16*)alloc((size_t)12 * 192 * 96 * 2);
    float* db1f = (float*)alloc(40 * 4);
    float* db2f = (float*)alloc(80 * 4);
    float* db3f = (float*)alloc(160 * 4);
    float* pb1f = (float*)alloc(40 * 4);
    float* pb2f = (float*)alloc(80 * 4);
    float* pb3f = (float*)alloc(160 * 4);
    float* dattbF = (float*)alloc(160 * 4);
    float* pattbF = (float*)alloc(160 * 4);
    float* attbF  = (float*)alloc(160 * 4);
    float* fc1bF = (float*)alloc(1024 * 4);
    float* fc2bF = (float*)alloc(1024 * 4);
    float* fc3bF = (float*)alloc(512 * 4);
    float* outbF = (float*)alloc(2 * 4);
    bf16* dattWB = (bf16*)alloc(25600 * 2);
    bf16* pattWB = (bf16*)alloc(25600 * 2);
    bf16* wattB  = (bf16*)alloc(25600 * 2);
    bf16* d1  = (bf16*)alloc((size_t)NB * 40 * 62 * 2);     // rows padded 61->62
    bf16* d2  = (bf16*)alloc((size_t)NB * 80 * 56 * 2);
    bf16* dcB = (bf16*)alloc((size_t)NB * 160 * 49 * 2);
    bf16* p1  = (bf16*)alloc((size_t)NB * 40 * 1198 * 2);   // rows padded 1197->1198
    bf16* p2  = (bf16*)alloc((size_t)NB * 80 * 1190 * 2);
    bf16* pcB = (bf16*)alloc((size_t)NB * 160 * 1179 * 2);
    float* datt  = (float*)alloc((size_t)NB * 49 * 160 * 4);
    bf16* pattB = (bf16*)alloc((size_t)NB * 1179 * 160 * 2);
    float* Mdpart = (float*)alloc((size_t)NB * 32 * 49 * 160 * 4);
    bf16* MpW  = (bf16*)alloc((size_t)NB * 1184 * 160 * 2);
    float* pair = (float*)alloc(NB * 320 * 4);
    float* h1 = (float*)alloc(NB * 1024 * 4);
    float* h2 = (float*)alloc(NB * 1024 * 4);
    float* h3 = (float*)alloc(NB * 512 * 4);

    // 1) dtype sniff
    sniff_kernel<<<1, 256, 0, stream>>>((const unsigned short*)fc2W, flag);

    // 2) unified prep: flattened 1D grid (zero empty blocks)
    CvtJob cj;
    PackJob pj;
    PrepOff po;
    int si = 0, running = 0;
    auto add = [&](const void* s, float* d, int n) {
        cj.src[si] = s; cj.dst[si] = d; po.off[si] = running; running += n; si++;
    };
    add(db1, db1f, 40); add(db2, db2f, 80); add(db3, db3f, 160);
    add(pb1, pb1f, 40); add(pb2, pb2f, 80); add(pb3, pb3f, 160);
    add(dattb, dattbF, 160); add(pattb, pattbF, 160); add(attb, attbF, 160);
    add(fc1b, fc1bF, 1024); add(fc2b, fc2bF, 1024); add(fc3b, fc3bF, 512);
    add(outb, outbF, 2);
    add(nullptr, pair, NB * 320);
    int pi = 0;
    auto seg = [&](const void* s, bf16* d, int Cout, int CIN, int K, int coP, int CIP) {
        pj.src[pi] = s; pj.dst[pi] = d;
        pj.Cout[pi] = Cout; pj.CIN[pi] = CIN; pj.K[pi] = K; pj.coP[pi] = coP; pj.CIP[pi] = CIP;
        po.off[NSEG + pi] = running; running += K * coP * CIP; pi++;
    };
    seg(dW1, dW1p, 40, 64, 4, 48, 64);
    seg(pW1, pW1p, 40, 64, 4, 48, 64);
    seg(dW2, dW2p, 80, 40, 6, 128, 64);
    seg(pW2, pW2p, 80, 40, 8, 128, 64);
    seg(dW3, dW3p, 160, 80, 8, 192, 96);
    seg(pW3, pW3p, 160, 80, 12, 192, 96);
    seg(dattW, dattWB, 160, 160, 1, 160, 160);
    seg(pattW, pattWB, 160, 160, 1, 160, 160);
    seg(attW,  wattB,  160, 160, 1, 160, 160);
    seg(drug_emb, embDB, 65, 64, 1, 65, 64);
    seg(prot_emb, embPB, 26, 64, 1, 26, 64);
    po.off[NSEG + NPK] = running;
    prep<<<(running + 255) / 256, 256, 0, stream>>>(cj, pj, po, flag);

    // 3) CNN stacks: conv1, conv2, conv3 fused with att_proj (all vector-staged)
    conv1_mfma<<<16 + 16 * 19, 256, 0, stream>>>(drug_tok, prot_tok, embDB, embPB,
                                                 dW1p, pW1p, db1f, pb1f, d1, p1);
    conv_dual<6, 8, 40, 2, 5><<<320, 320, 0, stream>>>(
        d1, dW2p, db2f, d2, 61, 62, 56,
        p1, pW2p, pb2f, p2, 1197, 1198, 1190, 80, 128);
    conv3_proj<8, 12, 80, 3, 10><<<320, 640, 0, stream>>>(
        d2, dW3p, db3f, dcB, 56, 49,
        p2, pW3p, pb3f, pcB, 1190, 1179, 160, 192,
        dattWB, pattWB, dattbF, pattbF, datt, pattB);

    // 4) fused pairwise relu-means (v9 structure)
    mean_fused<<<16 * 32, 640, 0, stream>>>(datt, pattB, MpW, Mdpart);

    // 5) fused attW-GEMM + sigmoid + scale + maxpool (+ inline Md reduction)
    att_sig_mfma<<<320, 640, 0, stream>>>(Mdpart, MpW, wattB, attbF, dcB, pcB, pair);

    // 6) MLP head (block-per-output GEMV)
    fc_block<<<1024, 256, 0, stream>>>(pair, fc1W, fc1bF, h1, 320, 1024, flag);
    fc_block<<<1024, 256, 0, stream>>>(h1, fc2W, fc2bF, h2, 1024, 1024, flag);
    fc_block<<<512, 256, 0, stream>>>(h2, fc3W, fc3bF, h3, 1024, 512, flag);
    out_block<<<2, 256, 0, stream>>>(h3, outW, outbF, d_out, flag);
}

// Round 10
// 223.878 us; speedup vs baseline: 1.0800x; 1.0672x over previous
//
#include <hip/hip_runtime.h>
#include <hip/hip_bf16.h>

typedef __hip_bfloat16 bf16;
typedef __attribute__((ext_vector_type(8))) short short8;
typedef __attribute__((ext_vector_type(4))) float floatx4;

#define NB 16
#define NPC 48   // mean_fused p-chunks of 25: 48*25=1200 >= 1179; 3 blocks/CU

// drug conv chain:  L 64 ->61(K4,C40) ->56(K6,C80) ->49(K8,C160)   (d1 rows padded to 62)
// prot conv chain:  L 1200 ->1197(K4,C40) ->1190(K8,C80) ->1179(K12,C160)  (p1 rows padded to 1198)

__device__ __forceinline__ float b2f(bf16 x) { return __bfloat162float(x); }
__device__ __forceinline__ float u16bf(unsigned short u) {
    return __uint_as_float(((unsigned)u) << 16);
}
__device__ __forceinline__ unsigned short f2bu(float v) {
    union { bf16 h; unsigned short u; } cv;
    cv.h = __float2bfloat16(v);
    return cv.u;
}

// ---------------- dtype sniffer (R4-proven) ----------------
__global__ void sniff_kernel(const unsigned short* __restrict__ w, int* __restrict__ flag) {
    __shared__ int cnt;
    if (threadIdx.x == 0) cnt = 0;
    __syncthreads();
    int hits = 0;
    for (int s = 0; s < 4; s++) {
        unsigned short u = w[(threadIdx.x * 4 + s) * 2];
        float v = fabsf(u16bf(u));
        if (v > 1e-6f && v < 2.0f) hits++;
    }
    atomicAdd(&cnt, hits);
    __syncthreads();
    if (threadIdx.x == 0) *flag = (cnt > 512) ? 1 : 0;
}

// ---------------- unified prep: flattened 1D (v12) ----------------
#define NSEG 14
struct CvtJob {
    const void* src[NSEG];
    float* dst[NSEG];
};
#define NPK 11
struct PackJob {
    const void* src[NPK];
    bf16* dst[NPK];
    short Cout[NPK], CIN[NPK], K[NPK], coP[NPK], CIP[NPK];
};
struct PrepOff { int off[NSEG + NPK + 1]; };

__global__ void prep(CvtJob cj, PackJob pj, PrepOff po, const int* __restrict__ flagp) {
    int g = blockIdx.x * 256 + threadIdx.x;
    if (g >= po.off[NSEG + NPK]) return;
    int s = 0;
#pragma unroll
    for (int t = 1; t < NSEG + NPK; t++)
        if (g >= po.off[t]) s = t;
    int i = g - po.off[s];
    if (s < NSEG) {
        const void* sp = cj.src[s];
        if (sp == nullptr) { cj.dst[s][i] = 0.f; return; }
        cj.dst[s][i] = (*flagp) ? b2f(((const bf16*)sp)[i]) : ((const float*)sp)[i];
    } else {
        int p = s - NSEG;
        int Cout = pj.Cout[p], CIN = pj.CIN[p];
        int coP = pj.coP[p], CIP = pj.CIP[p];
        int ci = i % CIP;
        int t = i / CIP;
        int co = t % coP;
        int k = t / coP;
        float v = 0.f;
        if (co < Cout && ci < CIN) {
            int si = (co * CIN + ci) * pj.K[p] + k;
            v = (*flagp) ? b2f(((const bf16*)pj.src[p])[si]) : ((const float*)pj.src[p])[si];
        }
        pj.dst[p][i] = __float2bfloat16(v);
    }
}

// ---------------- conv via MFMA implicit GEMM: shared body (v12) ----------------
template <int K, int CIN, int CHUNKS, int NW>
__device__ __forceinline__ void conv_body(unsigned short* xT,
                                          const unsigned short* xb,
                                          const unsigned short* wbase,
                                          const float* __restrict__ bias,
                                          bf16* __restrict__ y,
                                          int b, int Lin, int Lstride, int Lout,
                                          int Cout, int coP, int l0) {
    const int CIP = CHUNKS * 32;
    const int PCI = CIP + 8;
    const int TLX = 64 + K - 1;
    const int LV = (TLX + 7) >> 3;
    for (int i = threadIdx.x; i < CIP * LV; i += NW * 64) {
        int ci = i / LV, lv = (i - ci * LV) << 3;
        if (ci < CIN && lv + 8 <= TLX && l0 + lv + 8 <= Lin) {
            short8 v = *(const short8*)(xb + ci * Lstride + l0 + lv);
#pragma unroll
            for (int j = 0; j < 8; j++) xT[(lv + j) * PCI + ci] = (unsigned short)v[j];
        } else {
            for (int j = 0; j < 8; j++) {
                int l = lv + j;
                if (l >= TLX) break;
                int gl = l0 + l;
                xT[l * PCI + ci] = (ci < CIN && gl < Lin) ? xb[ci * Lstride + gl]
                                                          : (unsigned short)0;
            }
        }
    }
    __syncthreads();
    int lane = threadIdx.x & 63;
    int ct = threadIdx.x >> 6;       // wave id == ct tile
    int n = lane & 15, quad = lane >> 4;
    floatx4 acc[4];
#pragma unroll
    for (int i = 0; i < 4; i++) acc[i] = (floatx4){0.f, 0.f, 0.f, 0.f};
#pragma unroll
    for (int k = 0; k < K; k++) {
#pragma unroll
        for (int ch = 0; ch < CHUNKS; ch++) {
            short8 a = *(const short8*)(wbase +
                        ((size_t)(k * coP + ct * 16 + n)) * CIP + ch * 32 + quad * 8);
#pragma unroll
            for (int nt = 0; nt < 4; nt++) {
                short8 bb = *(const short8*)(xT + (nt * 16 + n + k) * PCI + ch * 32 + quad * 8);
                acc[nt] = __builtin_amdgcn_mfma_f32_16x16x32_bf16(a, bb, acc[nt], 0, 0, 0);
            }
        }
    }
    int m0 = quad * 4;
#pragma unroll
    for (int nt = 0; nt < 4; nt++) {
        int l = l0 + nt * 16 + n;
        if (l >= Lout) continue;
#pragma unroll
        for (int r = 0; r < 4; r++) {
            int co = ct * 16 + m0 + r;
            if (co < Cout)
                y[((size_t)b * Cout + co) * Lout + l] =
                    __float2bfloat16(fmaxf(acc[nt][r] + bias[co], 0.f));
        }
    }
}

// merged drug+prot conv (layer 2), NW waves = NW ct-tiles
template <int KD, int KP, int CIN, int CHUNKS, int NW>
__global__ __launch_bounds__(NW * 64) void conv_dual(const bf16* __restrict__ xd,
                                                 const bf16* __restrict__ Wpd,
                                                 const float* __restrict__ bd,
                                                 bf16* __restrict__ yd,
                                                 int LinD, int LsD, int LoutD,
                                                 const bf16* __restrict__ xp,
                                                 const bf16* __restrict__ Wpp,
                                                 const float* __restrict__ bp,
                                                 bf16* __restrict__ yp,
                                                 int LinP, int LsP, int LoutP,
                                                 int Cout, int coP) {
    const int CIP = CHUNKS * 32;
    const int PCI = CIP + 8;
    const int TLXMAX = 64 + KP - 1;   // KP >= KD
    __shared__ __align__(16) unsigned short xT[TLXMAX * PCI];
    if (blockIdx.x < 16) {
        int b = blockIdx.x;
        conv_body<KD, CIN, CHUNKS, NW>(xT, (const unsigned short*)xd + (size_t)b * CIN * LsD,
                                   (const unsigned short*)Wpd, bd, yd, b, LinD, LsD, LoutD,
                                   Cout, coP, 0);
    } else {
        int bx = blockIdx.x - 16;
        int b = bx / 19, l0 = (bx % 19) << 6;
        conv_body<KP, CIN, CHUNKS, NW>(xT, (const unsigned short*)xp + (size_t)b * CIN * LsP,
                                   (const unsigned short*)Wpp, bp, yp, b, LinP, LsP, LoutP,
                                   Cout, coP, l0);
    }
}

// ---------------- conv3 + att_proj FUSED (v11) with v12 vectorized staging ----------------
template <int K, int CIN, int CHUNKS, int NW>
__device__ __forceinline__ void conv_proj_phase(unsigned short* xT, unsigned short* xP,
                                                const unsigned short* xb,
                                                const unsigned short* wbase,
                                                const float* __restrict__ bias,
                                                unsigned short* __restrict__ y,
                                                int b, int Lin, int Lout,
                                                int Cout, int coP, int l0) {
    const int CIP = CHUNKS * 32;
    const int PCI = CIP + 8;
    const int TLX = 64 + K - 1;
    const int LV = (TLX + 7) >> 3;
    for (int i = threadIdx.x; i < CIP * LV; i += NW * 64) {
        int ci = i / LV, lv = (i - ci * LV) << 3;
        if (ci < CIN && lv + 8 <= TLX && l0 + lv + 8 <= Lin) {
            short8 v = *(const short8*)(xb + ci * Lin + l0 + lv);
#pragma unroll
            for (int j = 0; j < 8; j++) xT[(lv + j) * PCI + ci] = (unsigned short)v[j];
        } else {
            for (int j = 0; j < 8; j++) {
                int l = lv + j;
                if (l >= TLX) break;
                int gl = l0 + l;
                xT[l * PCI + ci] = (ci < CIN && gl < Lin) ? xb[ci * Lin + gl]
                                                          : (unsigned short)0;
            }
        }
    }
    __syncthreads();
    int lane = threadIdx.x & 63;
    int ct = threadIdx.x >> 6;
    int n = lane & 15, quad = lane >> 4;
    floatx4 acc[4];
#pragma unroll
    for (int i = 0; i < 4; i++) acc[i] = (floatx4){0.f, 0.f, 0.f, 0.f};
#pragma unroll
    for (int k = 0; k < K; k++) {
#pragma unroll
        for (int ch = 0; ch < CHUNKS; ch++) {
            short8 a = *(const short8*)(wbase +
                        ((size_t)(k * coP + ct * 16 + n)) * CIP + ch * 32 + quad * 8);
#pragma unroll
            for (int nt = 0; nt < 4; nt++) {
                short8 bb = *(const short8*)(xT + (nt * 16 + n + k) * PCI + ch * 32 + quad * 8);
                acc[nt] = __builtin_amdgcn_mfma_f32_16x16x32_bf16(a, bb, acc[nt], 0, 0, 0);
            }
        }
    }
    int m0 = quad * 4;
#pragma unroll
    for (int nt = 0; nt < 4; nt++) {
        int ll = nt * 16 + n;
        int l = l0 + ll;
#pragma unroll
        for (int r = 0; r < 4; r++) {
            int co = ct * 16 + m0 + r;
            float val = (l < Lout) ? fmaxf(acc[nt][r] + bias[co], 0.f) : 0.f;
            unsigned short u = f2bu(val);
            xP[ll * 168 + co] = u;                          // proj input tile
            if (l < Lout) y[((size_t)b * Cout + co) * Lout + l] = u;  // for att_sig
        }
    }
}

template <int KD, int KP, int CIN, int CHUNKS, int NW>
__global__ __launch_bounds__(NW * 64) void conv3_proj(
        const bf16* __restrict__ xd, const bf16* __restrict__ Wpd,
        const float* __restrict__ bd, bf16* __restrict__ yd, int LinD, int LoutD,
        const bf16* __restrict__ xp, const bf16* __restrict__ Wpp,
        const float* __restrict__ bp, bf16* __restrict__ yp, int LinP, int LoutP,
        int Cout, int coP,
        const bf16* __restrict__ dWB, const bf16* __restrict__ pWB,
        const float* __restrict__ dbF, const float* __restrict__ pbF,
        float* __restrict__ datt, bf16* __restrict__ pattB) {
    const int CIP = CHUNKS * 32;
    const int PCI = CIP + 8;
    const int TLXMAX = 64 + KP - 1;
    __shared__ __align__(16) unsigned short xT[TLXMAX * PCI];
    __shared__ __align__(16) unsigned short xP[64 * 168];
    bool isD = blockIdx.x < 16;
    int b, l0, L;
    if (isD) {
        b = blockIdx.x; l0 = 0; L = LoutD;
        conv_proj_phase<KD, CIN, CHUNKS, NW>(xT, xP,
            (const unsigned short*)xd + (size_t)b * CIN * LinD,
            (const unsigned short*)Wpd, bd, (unsigned short*)yd, b, LinD, LoutD, Cout, coP, 0);
    } else {
        int bx = blockIdx.x - 16;
        b = bx / 19; l0 = (bx % 19) << 6; L = LoutP;
        conv_proj_phase<KP, CIN, CHUNKS, NW>(xT, xP,
            (const unsigned short*)xp + (size_t)b * CIN * LinP,
            (const unsigned short*)Wpp, bp, (unsigned short*)yp, b, LinP, LoutP, Cout, coP, l0);
    }
    __syncthreads();
    // projection phase: wave t owns output tile t (0..NW-1), reads xP
    int lane = threadIdx.x & 63;
    int t = threadIdx.x >> 6;
    int n = lane & 15, quad = lane >> 4;
    const unsigned short* W = (const unsigned short*)(isD ? dWB : pWB);
    const float* pbias = isD ? dbF : pbF;
    floatx4 acc[4];
#pragma unroll
    for (int i = 0; i < 4; i++) acc[i] = (floatx4){0.f, 0.f, 0.f, 0.f};
#pragma unroll
    for (int ch = 0; ch < 5; ch++) {
        short8 a = *(const short8*)(W + ((size_t)(t * 16 + n)) * 160 + ch * 32 + quad * 8);
#pragma unroll
        for (int nt = 0; nt < 4; nt++) {
            short8 bb = *(const short8*)(xP + (nt * 16 + n) * 168 + ch * 32 + quad * 8);
            acc[nt] = __builtin_amdgcn_mfma_f32_16x16x32_bf16(a, bb, acc[nt], 0, 0, 0);
        }
    }
    int m0 = quad * 4;
    int o0 = t * 16 + m0;
#pragma unroll
    for (int nt = 0; nt < 4; nt++) {
        int l = l0 + nt * 16 + n;
        if (l >= L) continue;
        if (isD) {
            float4 v;
            v.x = acc[nt][0] + pbias[o0 + 0];
            v.y = acc[nt][1] + pbias[o0 + 1];
            v.z = acc[nt][2] + pbias[o0 + 2];
            v.w = acc[nt][3] + pbias[o0 + 3];
            *(float4*)(datt + ((size_t)b * 49 + l) * 160 + o0) = v;
        } else {
            ushort4 u;
            u.x = f2bu(acc[nt][0] + pbias[o0 + 0]);
            u.y = f2bu(acc[nt][1] + pbias[o0 + 1]);
            u.z = f2bu(acc[nt][2] + pbias[o0 + 2]);
            u.w = f2bu(acc[nt][3] + pbias[o0 + 3]);
            *(ushort4*)((unsigned short*)pattB + ((size_t)b * 1179 + l) * 160 + o0) = u;
        }
    }
}

// ---------------- conv1 via MFMA with embedding-gather staging (v12) ----------------
__global__ __launch_bounds__(256) void conv1_mfma(const int* __restrict__ dtok,
                                                  const int* __restrict__ ptok,
                                                  const bf16* __restrict__ embDB,
                                                  const bf16* __restrict__ embPB,
                                                  const bf16* __restrict__ dW1p,
                                                  const bf16* __restrict__ pW1p,
                                                  const float* __restrict__ db1f,
                                                  const float* __restrict__ pb1f,
                                                  bf16* __restrict__ d1,
                                                  bf16* __restrict__ p1) {
    const int K = 4, CIP = 64, PCI = 72, TLX = 67, coP = 48, Cout = 40;
    __shared__ __align__(16) unsigned short xT[TLX * PCI];
    __shared__ int stok[TLX];
    bool isD = blockIdx.x < 16;
    int b, l0, Lin, Lout, Ostride;
    const int* tok; const unsigned short* embB; const unsigned short* Wp;
    const float* bias; bf16* y;
    if (isD) {
        b = blockIdx.x; l0 = 0; Lin = 64; Lout = 61; Ostride = 62;
        tok = dtok; embB = (const unsigned short*)embDB;
        Wp = (const unsigned short*)dW1p; bias = db1f; y = d1;
    } else {
        int bx = blockIdx.x - 16;
        b = bx / 19; l0 = (bx % 19) << 6; Lin = 1200; Lout = 1197; Ostride = 1198;
        tok = ptok; embB = (const unsigned short*)embPB;
        Wp = (const unsigned short*)pW1p; bias = pb1f; y = p1;
    }
    if (threadIdx.x < TLX) {
        int l = l0 + threadIdx.x;
        stok[threadIdx.x] = (l < Lin) ? tok[b * Lin + l] : -1;
    }
    __syncthreads();
    for (int i = threadIdx.x; i < TLX * 8; i += 256) {
        int l = i >> 3, c8 = (i & 7) << 3;
        int t = stok[l];
        short8 v = (short8){0, 0, 0, 0, 0, 0, 0, 0};
        if (t >= 0) v = *(const short8*)(embB + t * 64 + c8);
        *(short8*)(xT + l * PCI + c8) = v;
    }
    __syncthreads();
    int lane = threadIdx.x & 63;
    int w = threadIdx.x >> 6;
    int n = lane & 15, quad = lane >> 4;
    if (w >= 3) return;
    floatx4 acc[4];
#pragma unroll
    for (int i = 0; i < 4; i++) acc[i] = (floatx4){0.f, 0.f, 0.f, 0.f};
#pragma unroll
    for (int k = 0; k < K; k++) {
#pragma unroll
        for (int ch = 0; ch < 2; ch++) {
            short8 a = *(const short8*)(Wp +
                        ((size_t)(k * coP + w * 16 + n)) * CIP + ch * 32 + quad * 8);
#pragma unroll
            for (int nt = 0; nt < 4; nt++) {
                short8 bb = *(const short8*)(xT + (nt * 16 + n + k) * PCI + ch * 32 + quad * 8);
                acc[nt] = __builtin_amdgcn_mfma_f32_16x16x32_bf16(a, bb, acc[nt], 0, 0, 0);
            }
        }
    }
    int m0 = quad * 4;
#pragma unroll
    for (int nt = 0; nt < 4; nt++) {
        int l = l0 + nt * 16 + n;
        if (l >= Lout) continue;
#pragma unroll
        for (int r = 0; r < 4; r++) {
            int co = w * 16 + m0 + r;
            if (co < Cout)
                y[((size_t)b * Cout + co) * Ostride + l] =
                    __float2bfloat16(fmaxf(acc[nt][r] + bias[co], 0.f));
        }
    }
}

// ---------------- fused means v13: 48 chunks of 25 -> 3 blocks/CU ----------------
__global__ __launch_bounds__(640) void mean_fused(const float* __restrict__ datt,
                                                  const bf16* __restrict__ patt,
                                                  bf16* __restrict__ MpW,
                                                  float* __restrict__ Mdpart) {
    __shared__ __align__(16) unsigned short sp[25 * 160];
    int tid = threadIdx.x;
    int b = blockIdx.x / NPC;
    int pc = blockIdx.x % NPC;
    int p0 = pc * 25;
    int pmax = 1179 - p0;
    if (pmax > 25) pmax = 25;
    // stage p-tile (coalesced short8): sp[pi][k] = patt[b][p0+pi][k]
    {
        const short8* src = (const short8*)((const unsigned short*)patt +
                                            ((size_t)b * 1179 + p0) * 160);
        short8* dst = (short8*)sp;
        int n8 = (pmax * 160) >> 3;   // exact (160*pmax % 8 == 0)
        for (int v = tid; v < n8; v += 640) dst[v] = src[v];
    }
    int h = tid & 3;
    int k = tid >> 2;                 // 0..159
    int d0 = h * 13;                  // 0,13,26,39
    int nd = (h == 3) ? 10 : 13;      // 13+13+13+10 = 49
    const float* drow = datt + (size_t)b * 49 * 160 + k;
    float dv[13], md[13];
#pragma unroll
    for (int i = 0; i < 13; i++) {
        // pad slots: dv=-1e30 -> relu(dv+pv)==0, contributes nothing
        dv[i] = (i < nd) ? drow[(d0 + i) * 160] : -1e30f;
        md[i] = 0.f;
    }
    __syncthreads();
    unsigned short* mp = (unsigned short*)MpW + ((size_t)b * 1184 + p0) * 160 + k;
#pragma unroll 2
    for (int pi = 0; pi < pmax; pi++) {
        float pv = u16bf(sp[pi * 160 + k]);
        float s0 = 0.f, s1 = 0.f, s2 = 0.f, s3 = 0.f;
#pragma unroll
        for (int g = 0; g < 3; g++) {
            float r0 = fmaxf(dv[g * 4 + 0] + pv, 0.f);
            float r1 = fmaxf(dv[g * 4 + 1] + pv, 0.f);
            float r2 = fmaxf(dv[g * 4 + 2] + pv, 0.f);
            float r3 = fmaxf(dv[g * 4 + 3] + pv, 0.f);
            md[g * 4 + 0] += r0; s0 += r0;
            md[g * 4 + 1] += r1; s1 += r1;
            md[g * 4 + 2] += r2; s2 += r2;
            md[g * 4 + 3] += r3; s3 += r3;
        }
        {
            float r = fmaxf(dv[12] + pv, 0.f);
            md[12] += r; s0 += r;
        }
        float s = (s0 + s1) + (s2 + s3);
        s += __shfl_xor(s, 1, 64);    // combine 4 d-quarters (lanes 4k..4k+3)
        s += __shfl_xor(s, 2, 64);
        if (h == 0) mp[(size_t)pi * 160] = f2bu(s * (1.f / 49.f));
    }
    // streaming partial store: [b][pc][d][k], wave-coalesced runs, no RMW
    float* op = Mdpart + (((size_t)b * NPC + pc) * 49) * 160 + k;
#pragma unroll
    for (int i = 0; i < 13; i++)
        if (i < nd) op[(d0 + i) * 160] = md[i];
}

// sum the NPC p-chunk partials -> Md[b][49][160] (490 blocks = full-BW spread;
// v11's in-att_sig fold made 16 blocks pull 16MB -> ~20us straggler. Reverted.)
__global__ __launch_bounds__(256) void md_reduce(const float* __restrict__ Mdpart,
                                                 float* __restrict__ Md) {
    int i = blockIdx.x * 256 + threadIdx.x;
    if (i >= NB * 49 * 160) return;
    int b = i / (49 * 160);
    int dk = i - b * (49 * 160);
    const float* src = Mdpart + (size_t)b * NPC * 7840 + dk;
    float s0 = 0.f, s1 = 0.f, s2 = 0.f, s3 = 0.f;
#pragma unroll
    for (int pc = 0; pc < NPC; pc += 4) {
        s0 += src[(size_t)(pc + 0) * 7840];
        s1 += src[(size_t)(pc + 1) * 7840];
        s2 += src[(size_t)(pc + 2) * 7840];
        s3 += src[(size_t)(pc + 3) * 7840];
    }
    Md[i] = (s0 + s1) + (s2 + s3);
}

// ---------------- att_sig via MFMA + fused sigmoid/scale/maxpool ----------------
// v13: d-path reads small Md again (straggler removed); p-path staging short8.
__global__ __launch_bounds__(640) void att_sig_mfma(const float* __restrict__ Md,
                                                    const bf16* __restrict__ MpW,
                                                    const bf16* __restrict__ wattB,
                                                    const float* __restrict__ attbF,
                                                    const bf16* __restrict__ dcB,
                                                    const bf16* __restrict__ pcB,
                                                    float* __restrict__ pair) {
    const int PCI = 168;
    __shared__ __align__(16) unsigned short sM[64 * PCI];
    bool isD = blockIdx.x < 16;
    int b, p0, L, off;
    const unsigned short* conv;
    if (isD) {
        b = blockIdx.x; p0 = 0; L = 49; off = 0; conv = (const unsigned short*)dcB;
        for (int i = threadIdx.x; i < 160 * 64; i += 640) {
            int r = i / 160, k = i - r * 160;
            float v = (r < 49) ? Md[((size_t)b * 49 + r) * 160 + k] * (1.f / 1179.f) : 0.f;
            sM[r * PCI + k] = f2bu(v);
        }
    } else {
        int bx = blockIdx.x - 16;
        b = bx / 19; p0 = (bx % 19) << 6; L = 1179; off = 160;
        conv = (const unsigned short*)pcB;
        const unsigned short* mb = (const unsigned short*)MpW + (size_t)b * 1184 * 160;
        for (int i = threadIdx.x; i < 64 * 20; i += 640) {   // 20 short8 per 160-row
            int r = i / 20, k8 = (i - r * 20) << 3;
            int p = p0 + r;
            short8 v = (short8){0, 0, 0, 0, 0, 0, 0, 0};
            if (p < 1179) v = *(const short8*)(mb + (size_t)p * 160 + k8);
            *(short8*)(sM + r * PCI + k8) = v;
        }
    }
    __syncthreads();
    int lane = threadIdx.x & 63;
    int t = threadIdx.x >> 6;        // wave id == t tile, 0..9
    int n = lane & 15, quad = lane >> 4;
    floatx4 acc[4];
#pragma unroll
    for (int i = 0; i < 4; i++) acc[i] = (floatx4){0.f, 0.f, 0.f, 0.f};
    const unsigned short* W = (const unsigned short*)wattB;
#pragma unroll
    for (int ch = 0; ch < 5; ch++) {
        short8 a = *(const short8*)(W + ((size_t)(t * 16 + n)) * 160 + ch * 32 + quad * 8);
#pragma unroll
        for (int nt = 0; nt < 4; nt++) {
            short8 bb = *(const short8*)(sM + (nt * 16 + n) * PCI + ch * 32 + quad * 8);
            acc[nt] = __builtin_amdgcn_mfma_f32_16x16x32_bf16(a, bb, acc[nt], 0, 0, 0);
        }
    }
    int m0 = quad * 4;
    float vmax[4] = {0.f, 0.f, 0.f, 0.f};
#pragma unroll
    for (int nt = 0; nt < 4; nt++) {
        int p = p0 + nt * 16 + n;
#pragma unroll
        for (int r = 0; r < 4; r++) {
            int o = t * 16 + m0 + r;
            float sig = 1.f / (1.f + __expf(-(acc[nt][r] + attbF[o])));
            float v = 0.f;
            if (p < L) v = u16bf(conv[((size_t)b * 160 + o) * L + p]) * (0.5f + sig);
            vmax[r] = fmaxf(vmax[r], v);
        }
    }
#pragma unroll
    for (int m = 1; m < 16; m <<= 1) {
#pragma unroll
        for (int r = 0; r < 4; r++)
            vmax[r] = fmaxf(vmax[r], __shfl_xor(vmax[r], m, 64));
    }
    if (n == 0) {
#pragma unroll
        for (int r = 0; r < 4; r++)
            atomicMax((unsigned int*)(pair + b * 320 + off + t * 16 + m0 + r),
                      __float_as_uint(vmax[r]));
    }
}

// ---------------- MLP: block-per-output GEMV (R9-proven) ----------------
__global__ __launch_bounds__(256) void fc_block(const float* __restrict__ in,
                                                const void* __restrict__ W,
                                                const float* __restrict__ bias,
                                                float* __restrict__ out,
                                                int IN, int OUT,
                                                const int* __restrict__ flagp) {
    int j = blockIdx.x;
    int w = threadIdx.x >> 6, li = threadIdx.x & 63;
    int nv = IN >> 2;
    const float4* i0 = (const float4*)(in + (size_t)(w * 4 + 0) * IN);
    const float4* i1 = (const float4*)(in + (size_t)(w * 4 + 1) * IN);
    const float4* i2 = (const float4*)(in + (size_t)(w * 4 + 2) * IN);
    const float4* i3 = (const float4*)(in + (size_t)(w * 4 + 3) * IN);
    float p0 = 0.f, p1 = 0.f, p2 = 0.f, p3 = 0.f;
    if (*flagp) {
        const ushort4* w4 = (const ushort4*)((const unsigned short*)W + (size_t)j * IN);
        for (int v = li; v < nv; v += 64) {
            ushort4 u = w4[v];
            float wa = u16bf(u.x), wb = u16bf(u.y), wc = u16bf(u.z), wd = u16bf(u.w);
            float4 x;
            x = i0[v]; p0 += x.x * wa + x.y * wb + x.z * wc + x.w * wd;
            x = i1[v]; p1 += x.x * wa + x.y * wb + x.z * wc + x.w * wd;
            x = i2[v]; p2 += x.x * wa + x.y * wb + x.z * wc + x.w * wd;
            x = i3[v]; p3 += x.x * wa + x.y * wb + x.z * wc + x.w * wd;
        }
    } else {
        const float4* w4 = (const float4*)((const float*)W + (size_t)j * IN);
        for (int v = li; v < nv; v += 64) {
            float4 u = w4[v];
            float4 x;
            x = i0[v]; p0 += x.x * u.x + x.y * u.y + x.z * u.z + x.w * u.w;
            x = i1[v]; p1 += x.x * u.x + x.y * u.y + x.z * u.z + x.w * u.w;
            x = i2[v]; p2 += x.x * u.x + x.y * u.y + x.z * u.z + x.w * u.w;
            x = i3[v]; p3 += x.x * u.x + x.y * u.y + x.z * u.z + x.w * u.w;
        }
    }
#pragma unroll
    for (int m = 1; m < 64; m <<= 1) {
        p0 += __shfl_xor(p0, m, 64);
        p1 += __shfl_xor(p1, m, 64);
        p2 += __shfl_xor(p2, m, 64);
        p3 += __shfl_xor(p3, m, 64);
    }
    if (li == 0) {
        float bj = bias[j];
        float o0 = p0 + bj, o1 = p1 + bj, o2 = p2 + bj, o3 = p3 + bj;
        o0 = o0 > 0.f ? o0 : 0.01f * o0;
        o1 = o1 > 0.f ? o1 : 0.01f * o1;
        o2 = o2 > 0.f ? o2 : 0.01f * o2;
        o3 = o3 > 0.f ? o3 : 0.01f * o3;
        out[(size_t)(w * 4 + 0) * OUT + j] = o0;
        out[(size_t)(w * 4 + 1) * OUT + j] = o1;
        out[(size_t)(w * 4 + 2) * OUT + j] = o2;
        out[(size_t)(w * 4 + 3) * OUT + j] = o3;
    }
}

__global__ __launch_bounds__(256) void out_block(const float* __restrict__ h,
                                                 const void* __restrict__ W,
                                                 const float* __restrict__ biasF,
                                                 void* __restrict__ out,
                                                 const int* __restrict__ flagp) {
    int j = blockIdx.x;
    int w = threadIdx.x >> 6, li = threadIdx.x & 63;
    const int IN = 512, nv = 128;
    const float4* i0 = (const float4*)(h + (size_t)(w * 4 + 0) * IN);
    const float4* i1 = (const float4*)(h + (size_t)(w * 4 + 1) * IN);
    const float4* i2 = (const float4*)(h + (size_t)(w * 4 + 2) * IN);
    const float4* i3 = (const float4*)(h + (size_t)(w * 4 + 3) * IN);
    float p0 = 0.f, p1 = 0.f, p2 = 0.f, p3 = 0.f;
    int flag = *flagp;
    if (flag) {
        const ushort4* w4 = (const ushort4*)((const unsigned short*)W + (size_t)j * IN);
        for (int v = li; v < nv; v += 64) {
            ushort4 u = w4[v];
            float wa = u16bf(u.x), wb = u16bf(u.y), wc = u16bf(u.z), wd = u16bf(u.w);
            float4 x;
            x = i0[v]; p0 += x.x * wa + x.y * wb + x.z * wc + x.w * wd;
            x = i1[v]; p1 += x.x * wa + x.y * wb + x.z * wc + x.w * wd;
            x = i2[v]; p2 += x.x * wa + x.y * wb + x.z * wc + x.w * wd;
            x = i3[v]; p3 += x.x * wa + x.y * wb + x.z * wc + x.w * wd;
        }
    } else {
        const float4* w4 = (const float4*)((const float*)W + (size_t)j * IN);
        for (int v = li; v < nv; v += 64) {
            float4 u = w4[v];
            float4 x;
            x = i0[v]; p0 += x.x * u.x + x.y * u.y + x.z * u.z + x.w * u.w;
            x = i1[v]; p1 += x.x * u.x + x.y * u.y + x.z * u.z + x.w * u.w;
            x = i2[v]; p2 += x.x * u.x + x.y * u.y + x.z * u.z + x.w * u.w;
            x = i3[v]; p3 += x.x * u.x + x.y * u.y + x.z * u.z + x.w * u.w;
        }
    }
#pragma unroll
    for (int m = 1; m < 64; m <<= 1) {
        p0 += __shfl_xor(p0, m, 64);
        p1 += __shfl_xor(p1, m, 64);
        p2 += __shfl_xor(p2, m, 64);
        p3 += __shfl_xor(p3, m, 64);
    }
    if (li == 0) {
        float bj = biasF[j];
        float o0 = p0 + bj, o1 = p1 + bj, o2 = p2 + bj, o3 = p3 + bj;
        if (flag) {
            bf16* ob = (bf16*)out;
            ob[(w * 4 + 0) * 2 + j] = __float2bfloat16(o0);
            ob[(w * 4 + 1) * 2 + j] = __float2bfloat16(o1);
            ob[(w * 4 + 2) * 2 + j] = __float2bfloat16(o2);
            ob[(w * 4 + 3) * 2 + j] = __float2bfloat16(o3);
        } else {
            float* of = (float*)out;
            of[(w * 4 + 0) * 2 + j] = o0;
            of[(w * 4 + 1) * 2 + j] = o1;
            of[(w * 4 + 2) * 2 + j] = o2;
            of[(w * 4 + 3) * 2 + j] = o3;
        }
    }
}

extern "C" void kernel_launch(void* const* d_in, const int* in_sizes, int n_in,
                              void* d_out, int out_size, void* d_ws, size_t ws_size,
                              hipStream_t stream) {
    const int* drug_tok = (const int*)d_in[0];
    const int* prot_tok = (const int*)d_in[1];
    const void* drug_emb = d_in[2];
    const void* prot_emb = d_in[3];
    const void* dW1 = d_in[4];  const void* db1 = d_in[5];
    const void* dW2 = d_in[6];  const void* db2 = d_in[7];
    const void* dW3 = d_in[8];  const void* db3 = d_in[9];
    const void* pW1 = d_in[10]; const void* pb1 = d_in[11];
    const void* pW2 = d_in[12]; const void* pb2 = d_in[13];
    const void* pW3 = d_in[14]; const void* pb3 = d_in[15];
    const void* dattW = d_in[16]; const void* dattb = d_in[17];
    const void* pattW = d_in[18]; const void* pattb = d_in[19];
    const void* attW  = d_in[20]; const void* attb  = d_in[21];
    const void* fc1W = d_in[22]; const void* fc1b = d_in[23];
    const void* fc2W = d_in[24]; const void* fc2b = d_in[25];
    const void* fc3W = d_in[26]; const void* fc3b = d_in[27];
    const void* outW = d_in[28]; const void* outb = d_in[29];

    char* base = (char*)d_ws;
    size_t cur = 0;
    auto alloc = [&](size_t bytes) -> char* {
        char* p = base + cur;
        cur = (cur + bytes + 255) & ~(size_t)255;
        return p;
    };
    int*   flag  = (int*)alloc(256);
    bf16* embDB = (bf16*)alloc(65 * 64 * 2);
    bf16* embPB = (bf16*)alloc(26 * 64 * 2);
    bf16* dW1p = (bf16*)alloc((size_t)4 * 48 * 64 * 2);
    bf16* pW1p = (bf16*)alloc((size_t)4 * 48 * 64 * 2);
    bf16* dW2p = (bf16*)alloc((size_t)6 * 128 * 64 * 2);
    bf16* dW3p = (bf16*)alloc((size_t)8 * 192 * 96 * 2);
    bf16* pW2p = (bf16*)alloc((size_t)8 * 128 * 64 * 2);
    bf16* pW3p = (bf16*)alloc((size_t)12 * 192 * 96 * 2);
    float* db1f = (float*)alloc(40 * 4);
    float* db2f = (float*)alloc(80 * 4);
    float* db3f = (float*)alloc(160 * 4);
    float* pb1f = (float*)alloc(40 * 4);
    float* pb2f = (float*)alloc(80 * 4);
    float* pb3f = (float*)alloc(160 * 4);
    float* dattbF = (float*)alloc(160 * 4);
    float* pattbF = (float*)alloc(160 * 4);
    float* attbF  = (float*)alloc(160 * 4);
    float* fc1bF = (float*)alloc(1024 * 4);
    float* fc2bF = (float*)alloc(1024 * 4);
    float* fc3bF = (float*)alloc(512 * 4);
    float* outbF = (float*)alloc(2 * 4);
    bf16* dattWB = (bf16*)alloc(25600 * 2);
    bf16* pattWB = (bf16*)alloc(25600 * 2);
    bf16* wattB  = (bf16*)alloc(25600 * 2);
    bf16* d1  = (bf16*)alloc((size_t)NB * 40 * 62 * 2);     // rows padded 61->62
    bf16* d2  = (bf16*)alloc((size_t)NB * 80 * 56 * 2);
    bf16* dcB = (bf16*)alloc((size_t)NB * 160 * 49 * 2);
    bf16* p1  = (bf16*)alloc((size_t)NB * 40 * 1198 * 2);   // rows padded 1197->1198
    bf16* p2  = (bf16*)alloc((size_t)NB * 80 * 1190 * 2);
    bf16* pcB = (bf16*)alloc((size_t)NB * 160 * 1179 * 2);
    float* datt  = (float*)alloc((size_t)NB * 49 * 160 * 4);
    bf16* pattB = (bf16*)alloc((size_t)NB * 1179 * 160 * 2);
    float* Md   = (float*)alloc((size_t)NB * 49 * 160 * 4);
    float* Mdpart = (float*)alloc((size_t)NB * NPC * 49 * 160 * 4);
    bf16* MpW  = (bf16*)alloc((size_t)NB * 1184 * 160 * 2);
    float* pair = (float*)alloc(NB * 320 * 4);
    float* h1 = (float*)alloc(NB * 1024 * 4);
    float* h2 = (float*)alloc(NB * 1024 * 4);
    float* h3 = (float*)alloc(NB * 512 * 4);

    // 1) dtype sniff
    sniff_kernel<<<1, 256, 0, stream>>>((const unsigned short*)fc2W, flag);

    // 2) unified prep: flattened 1D grid (zero empty blocks)
    CvtJob cj;
    PackJob pj;
    PrepOff po;
    int si = 0, running = 0;
    auto add = [&](const void* s, float* d, int n) {
        cj.src[si] = s; cj.dst[si] = d; po.off[si] = running; running += n; si++;
    };
    add(db1, db1f, 40); add(db2, db2f, 80); add(db3, db3f, 160);
    add(pb1, pb1f, 40); add(pb2, pb2f, 80); add(pb3, pb3f, 160);
    add(dattb, dattbF, 160); add(pattb, pattbF, 160); add(attb, attbF, 160);
    add(fc1b, fc1bF, 1024); add(fc2b, fc2bF, 1024); add(fc3b, fc3bF, 512);
    add(outb, outbF, 2);
    add(nullptr, pair, NB * 320);
    int pi = 0;
    auto seg = [&](const void* s, bf16* d, int Cout, int CIN, int K, int coP, int CIP) {
        pj.src[pi] = s; pj.dst[pi] = d;
        pj.Cout[pi] = Cout; pj.CIN[pi] = CIN; pj.K[pi] = K; pj.coP[pi] = coP; pj.CIP[pi] = CIP;
        po.off[NSEG + pi] = running; running += K * coP * CIP; pi++;
    };
    seg(dW1, dW1p, 40, 64, 4, 48, 64);
    seg(pW1, pW1p, 40, 64, 4, 48, 64);
    seg(dW2, dW2p, 80, 40, 6, 128, 64);
    seg(pW2, pW2p, 80, 40, 8, 128, 64);
    seg(dW3, dW3p, 160, 80, 8, 192, 96);
    seg(pW3, pW3p, 160, 80, 12, 192, 96);
    seg(dattW, dattWB, 160, 160, 1, 160, 160);
    seg(pattW, pattWB, 160, 160, 1, 160, 160);
    seg(attW,  wattB,  160, 160, 1, 160, 160);
    seg(drug_emb, embDB, 65, 64, 1, 65, 64);
    seg(prot_emb, embPB, 26, 64, 1, 26, 64);
    po.off[NSEG + NPK] = running;
    prep<<<(running + 255) / 256, 256, 0, stream>>>(cj, pj, po, flag);

    // 3) CNN stacks: conv1, conv2, conv3 fused with att_proj (all vector-staged)
    conv1_mfma<<<16 + 16 * 19, 256, 0, stream>>>(drug_tok, prot_tok, embDB, embPB,
                                                 dW1p, pW1p, db1f, pb1f, d1, p1);
    conv_dual<6, 8, 40, 2, 5><<<320, 320, 0, stream>>>(
        d1, dW2p, db2f, d2, 61, 62, 56,
        p1, pW2p, pb2f, p2, 1197, 1198, 1190, 80, 128);
    conv3_proj<8, 12, 80, 3, 10><<<320, 640, 0, stream>>>(
        d2, dW3p, db3f, dcB, 56, 49,
        p2, pW3p, pb3f, pcB, 1190, 1179, 160, 192,
        dattWB, pattWB, dattbF, pattbF, datt, pattB);

    // 4) fused pairwise relu-means (48 chunks, 3 blocks/CU) + full-BW reduce
    mean_fused<<<16 * NPC, 640, 0, stream>>>(datt, pattB, MpW, Mdpart);
    md_reduce<<<490, 256, 0, stream>>>(Mdpart, Md);

    // 5) fused attW-GEMM + sigmoid + scale + maxpool
    att_sig_mfma<<<320, 640, 0, stream>>>(Md, MpW, wattB, attbF, dcB, pcB, pair);

    // 6) MLP head (block-per-output GEMV)
    fc_block<<<1024, 256, 0, stream>>>(pair, fc1W, fc1bF, h1, 320, 1024, flag);
    fc_block<<<1024, 256, 0, stream>>>(h1, fc2W, fc2bF, h2, 1024, 1024, flag);
    fc_block<<<512, 256, 0, stream>>>(h2, fc3W, fc3bF, h3, 1024, 512, flag);
    out_block<<<2, 256, 0, stream>>>(h3, outW, outbF, d_out, flag);
}